// Round 4
// baseline (827.832 us; speedup 1.0000x reference)
//
#include <hip/hip_runtime.h>
#include <hip/hip_bf16.h>
#include <math.h>

#define DM   512
#define TT   1024
#define NB   4
#define NHD  8
#define LAYERS 6
#define DFFD 1024
#define MROWS (NB*TT)          // 4096
#define PERBUF (NB*NHD*TT*64)  // 2097152 elems per Q/K/V buffer

typedef __bf16 bf16x8 __attribute__((ext_vector_type(8)));
typedef __bf16 bf16x4 __attribute__((ext_vector_type(4)));
typedef float f32x4 __attribute__((ext_vector_type(4)));

// async global->LDS, 16B per lane; LDS base must be wave-uniform (m104/m108)
__device__ __forceinline__ void gl_lds16(const __bf16* g, __bf16* l) {
    __builtin_amdgcn_global_load_lds((const __attribute__((address_space(1))) void*)g,
                                     (__attribute__((address_space(3))) void*)l, 16, 0, 0);
}

// ---------------- embedding + positional encoding (fp32 h + bf16 shadow) ----------------
__global__ __launch_bounds__(256) void embed_pos_kernel(const int* __restrict__ x,
    const float* __restrict__ emb, float* __restrict__ h, __bf16* __restrict__ hb)
{
    int row = blockIdx.x;            // n*T + t
    int t = row & (TT - 1);
    int tok = x[row];
    const float* e = emb + (size_t)tok * DM;
    float* out = h + (size_t)row * DM;
    __bf16* outb = hb + (size_t)row * DM;
    for (int i = threadIdx.x; i < DM; i += 256) {
        float val = e[i] * 22.62741699796952f;   // sqrt(512)
        int pair = i >> 1;
        float rate = powf(10000.0f, -(float)pair * (1.0f / 256.0f));
        float ang = (float)t * rate;
        float pe = (i & 1) ? cosf(ang) : sinf(ang);
        float v = val + pe;
        out[i] = v;
        outb[i] = (__bf16)v;
    }
}

// ---------------- all-weight convert + transpose (one dispatch) ----------------
// W[K,N] fp32 -> Wt[N,K] bf16. For Wqkv, output columns are PERMUTED:
// original col c -> row (c%3)*512 + c/3, grouping Q|K|V with inner [h][d].
__global__ __launch_bounds__(256) void convert_all_kernel(
    const float* __restrict__ Wqkv, const float* __restrict__ Wff, const float* __restrict__ Wo,
    const float* __restrict__ bqkv,
    __bf16* __restrict__ WtQ, __bf16* __restrict__ WtF, __bf16* __restrict__ WtO,
    float* __restrict__ bqkv_p)
{
    __shared__ float tile[32][33];
    int l = blockIdx.z;
    int t = blockIdx.x;
    const float* W; __bf16* Wt; int K, N, bx, by; bool perm = false;
    if (t < 768)       { W = Wqkv; Wt = WtQ; K = 512;  N = 1536; bx = t & 15;  by = t >> 4; perm = true; }
    else if (t < 1280) { int u = t - 768;  W = Wff; Wt = WtF; K = 512;  N = 1024; bx = u & 15; by = u >> 4; }
    else               { int u = t - 1280; W = Wo;  Wt = WtO; K = 1024; N = 512;  bx = u & 31; by = u >> 5; }
    int k0 = bx * 32, n0 = by * 32;
    const float* Wl = W + (size_t)l * K * N;
    __bf16* Wtl = Wt + (size_t)l * K * N;
    int tx = threadIdx.x & 31, ty = threadIdx.x >> 5;   // ty 0..7
    #pragma unroll
    for (int i = ty; i < 32; i += 8)
        tile[i][tx] = Wl[(size_t)(k0 + i) * N + n0 + tx];
    if (perm && bx == 0 && ty == 0) {                   // permute bias once per col-chunk
        int c = n0 + tx;
        bqkv_p[l * 1536 + (c % 3) * 512 + c / 3] = bqkv[(size_t)l * 1536 + c];
    }
    __syncthreads();
    #pragma unroll
    for (int i = ty; i < 32; i += 8) {
        int c = n0 + i;
        int row = perm ? ((c % 3) * 512 + c / 3) : c;
        Wtl[(size_t)row * K + k0 + tx] = (__bf16)tile[tx][i];
    }
}

// ---------------- bf16 MFMA GEMM, 128x128 tile, DIRECT-GLOBAL operands (no LDS) ----------------
// K is small (512) and panels are L2-resident: each wave streams its A/B fragments
// straight from global (16B/lane dwordx4). No LDS, no barriers, no staging — LDS-read
// pipe unloaded, waves free-run, compiler pipelines loads under MFMAs with counted vmcnt.
// mode 1: relu -> bf16 Cb. mode 2: bf16 QKV scatter with PERMUTED columns:
// c in [0,512)=Q, [512,1024)=K (both [n,h,t,d]), [1024,1536)=V^T [n,h,d,t].
__global__ __launch_bounds__(256) void gemm_mfma(const __bf16* __restrict__ A,
    const __bf16* __restrict__ Bt, const float* __restrict__ bias,
    __bf16* __restrict__ Cb, int M, int Nc, int K, int mode)
{
    int tid = threadIdx.x;
    int lane = tid & 63;
    int wave = tid >> 6;
    int ln = lane & 15, q = lane >> 4;
    int wrow = (wave >> 1) * 64, wcol = (wave & 1) * 64;
    int n0 = blockIdx.x * 128, m0 = blockIdx.y * 128;

    f32x4 acc[4][4] = {};

    const __bf16* Arow0 = A  + (size_t)(m0 + wrow + ln) * K + q * 8;
    const __bf16* Brow0 = Bt + (size_t)(n0 + wcol + ln) * K + q * 8;

    for (int kp = 0; kp < K; kp += 32) {
        bf16x8 af[4], bfr[4];
        #pragma unroll
        for (int mt = 0; mt < 4; mt++)
            af[mt] = *(const bf16x8*)(Arow0 + (size_t)(mt * 16) * K + kp);
        #pragma unroll
        for (int nt = 0; nt < 4; nt++)
            bfr[nt] = *(const bf16x8*)(Brow0 + (size_t)(nt * 16) * K + kp);
        #pragma unroll
        for (int mt = 0; mt < 4; mt++)
            #pragma unroll
            for (int nt = 0; nt < 4; nt++)
                acc[mt][nt] = __builtin_amdgcn_mfma_f32_16x16x32_bf16(af[mt], bfr[nt], acc[mt][nt], 0, 0, 0);
    }

    #pragma unroll
    for (int mt = 0; mt < 4; mt++) {
        int mbase = m0 + wrow + mt * 16 + q * 4;
        if (mode == 1) {
            #pragma unroll
            for (int r = 0; r < 4; r++) {
                int m = mbase + r;
                #pragma unroll
                for (int nt = 0; nt < 4; nt++) {
                    int c = n0 + wcol + nt * 16 + ln;
                    float val = acc[mt][nt][r] + bias[c];
                    Cb[(size_t)m * Nc + c] = (__bf16)fmaxf(val, 0.f);
                }
            }
        } else {
            int n = mbase >> 10, t = mbase & (TT - 1);
            #pragma unroll
            for (int nt = 0; nt < 4; nt++) {
                int c = n0 + wcol + nt * 16 + ln;
                int buf = c >> 9;            // uniform within the 16-col group
                int hd = c & 511;
                int hh = hd >> 6, d = hd & 63;
                float bv = bias[c];
                if (buf == 2) {              // V^T [n,h,d,t]: 4 consecutive t -> one 8B store
                    size_t idx = 2 * (size_t)PERBUF + (((size_t)(n * NHD + hh) * 64 + d) << 10) + t;
                    bf16x4 v4;
                    #pragma unroll
                    for (int r = 0; r < 4; r++) v4[r] = (__bf16)(acc[mt][nt][r] + bv);
                    *(bf16x4*)&Cb[idx] = v4;
                } else {                     // Q,K [n,h,t,d]
                    size_t base = (size_t)buf * PERBUF + (((size_t)(n * NHD + hh) * TT + t) << 6) + d;
                    #pragma unroll
                    for (int r = 0; r < 4; r++)
                        Cb[base + (size_t)(r << 6)] = (__bf16)(acc[mt][nt][r] + bv);
                }
            }
        }
    }
}

// ---------------- FF2 GEMM, 128x64 tile, DIRECT-GLOBAL operands (no LDS) ----------------
__global__ __launch_bounds__(256) void gemm_ff2(const __bf16* __restrict__ A,
    const __bf16* __restrict__ Bt, const float* __restrict__ bias,
    float* __restrict__ C, int M, int Nc, int K)
{
    int tid = threadIdx.x;
    int lane = tid & 63;
    int wave = tid >> 6;
    int ln = lane & 15, q = lane >> 4;
    int wrow = (wave >> 1) * 64, wcol = (wave & 1) * 32;
    int n0 = blockIdx.x * 64, m0 = blockIdx.y * 128;

    f32x4 acc[4][2] = {};

    const __bf16* Arow0 = A  + (size_t)(m0 + wrow + ln) * K + q * 8;
    const __bf16* Brow0 = Bt + (size_t)(n0 + wcol + ln) * K + q * 8;

    for (int kp = 0; kp < K; kp += 32) {
        bf16x8 af[4], bfr[2];
        #pragma unroll
        for (int mt = 0; mt < 4; mt++)
            af[mt] = *(const bf16x8*)(Arow0 + (size_t)(mt * 16) * K + kp);
        #pragma unroll
        for (int nt = 0; nt < 2; nt++)
            bfr[nt] = *(const bf16x8*)(Brow0 + (size_t)(nt * 16) * K + kp);
        #pragma unroll
        for (int mt = 0; mt < 4; mt++)
            #pragma unroll
            for (int nt = 0; nt < 2; nt++)
                acc[mt][nt] = __builtin_amdgcn_mfma_f32_16x16x32_bf16(af[mt], bfr[nt], acc[mt][nt], 0, 0, 0);
    }

    #pragma unroll
    for (int mt = 0; mt < 4; mt++) {
        #pragma unroll
        for (int r = 0; r < 4; r++) {
            int m = m0 + wrow + mt * 16 + q * 4 + r;
            #pragma unroll
            for (int nt = 0; nt < 2; nt++) {
                int c = n0 + wcol + nt * 16 + ln;
                C[(size_t)m * Nc + c] = acc[mt][nt][r] + bias[c];
            }
        }
    }
}

// ---------------- split-KV MFMA flash attention (R1 structure: latency-bound, keep TLP) ----------------
// Q fragments in registers. K single-buffered + V double-buffered in LDS via
// async global_load_lds with XOR-swizzled source (linear dest, swizzled read:
// slot(r,c16) holds global block (r, c16^(r&7))). Separate padded P buffer.
// 2 barriers per KV tile; next K/V prefetch issued after the P barrier so its
// latency hides under the PV MFMAs. LDS 33.8 KB, 1280 blocks (~5/CU).
#define PPAD 72
#define NCHUNK 40
__global__ __launch_bounds__(256) void attn_partial_kernel(const __bf16* __restrict__ qb,
    const __bf16* __restrict__ kb, const __bf16* __restrict__ vtb,
    float* __restrict__ po, float* __restrict__ pden)
{
    __shared__ __align__(16) __bf16 Ksh[64 * 64];      // K tile [s][d], swizzled
    __shared__ __align__(16) __bf16 Vsh[2][64 * 64];   // V^T tile [d][s], swizzled
    __shared__ __align__(16) __bf16 Ps[64 * PPAD];     // P tile [q][s], padded

    int u = (NCHUNK - 1) - blockIdx.x;   // heavy chunks dispatch first
    int nh = blockIdx.y;
    int g, off;
    if (u < 4)       { g = 0; off = 0;  }
    else if (u < 12) { g = 1; off = 4;  }
    else if (u < 24) { g = 2; off = 12; }
    else             { g = 3; off = 24; }
    int rem = u - off;
    int nper = g + 1;
    int qq = rem / nper;           // 0..3
    int c  = rem - qq * nper;
    int qt = g * 4 + qq;
    int st0 = c * 4;
    int st1 = min(st0 + 4, qt + 1);

    int tid = threadIdx.x;
    int lane = tid & 63, w = tid >> 6;
    int ln = lane & 15, q = lane >> 4;

    const __bf16* Kg = kb + (size_t)nh * TT * 64;
    const __bf16* Vg = vtb + (size_t)nh * 64 * TT;   // [d][t]

    // Q fragments in registers: wave w owns q-rows w*16..+16 of this q-tile
    const __bf16* Qrow = qb + ((size_t)nh * TT + (size_t)qt * 64 + w * 16 + ln) * 64;
    bf16x8 aq0 = *(const bf16x8*)(Qrow + q * 8);
    bf16x8 aq1 = *(const bf16x8*)(Qrow + 32 + q * 8);

    // staging geometry: wave w issue i covers LDS bytes [(w*2+i)*1024, +1024)
    // lane l -> row (w*2+i)*8 + (l>>3), col16 l&7; source col pre-swizzled.
    int srow = lane >> 3;                        // 0..7  == (row & 7)
    int swz  = ((lane & 7) ^ srow) << 3;         // swizzled source col (elems)
    int r0 = (w * 2 + 0) * 8 + srow;
    int r1 = (w * 2 + 1) * 8 + srow;
    const __bf16* Kg0 = Kg + (size_t)r0 * 64 + swz;
    const __bf16* Kg1 = Kg + (size_t)r1 * 64 + swz;
    const __bf16* Vg0 = Vg + (size_t)r0 * TT + swz;
    const __bf16* Vg1 = Vg + (size_t)r1 * TT + swz;
    __bf16* Kd0 = Ksh + (w * 2 + 0) * 512;
    __bf16* Kd1 = Ksh + (w * 2 + 1) * 512;

    f32x4 o_acc[4] = {};
    float den_reg[4] = {0.f, 0.f, 0.f, 0.f};

    int cur = 0;
    gl_lds16(Kg0 + st0 * 4096, Kd0);
    gl_lds16(Kg1 + st0 * 4096, Kd1);
    gl_lds16(Vg0 + st0 * 64, Vsh[0] + (w * 2 + 0) * 512);
    gl_lds16(Vg1 + st0 * 64, Vsh[0] + (w * 2 + 1) * 512);

    int kswz = ln & 7;   // row&7 for all swizzled reads below (rows stride 16)
    for (int st = st0; st < st1; st++) {
        __syncthreads();   // staged K/V landed (vmcnt drain); prior P/V readers done

        // S = Q K^T for this wave's 16 q-rows x 64 key-cols
        f32x4 s_acc[4] = {};
        #pragma unroll
        for (int nt = 0; nt < 4; nt++) {
            int r = nt * 16 + ln;
            bf16x8 b0 = *(const bf16x8*)&Ksh[r * 64 + ((q ^ kswz) << 3)];
            s_acc[nt] = __builtin_amdgcn_mfma_f32_16x16x32_bf16(aq0, b0, s_acc[nt], 0, 0, 0);
            bf16x8 b1 = *(const bf16x8*)&Ksh[r * 64 + (((q + 4) ^ kswz) << 3)];
            s_acc[nt] = __builtin_amdgcn_mfma_f32_16x16x32_bf16(aq1, b1, s_acc[nt], 0, 0, 0);
        }

        // P = exp(S/8) with causal mask on diagonal tile; own rows -> Ps
        bool diag = (st == qt);
        #pragma unroll
        for (int nt = 0; nt < 4; nt++) {
            #pragma unroll
            for (int r = 0; r < 4; r++) {
                int lrow = w * 16 + q * 4 + r;
                int lcol = nt * 16 + ln;
                float p;
                if (diag && lcol > lrow) p = 0.f;
                else p = exp2f(s_acc[nt][r] * 0.18033688011112042f);  // /8 * log2(e)
                den_reg[r] += p;
                Ps[lrow * PPAD + lcol] = (__bf16)p;
            }
        }
        __syncthreads();   // P visible; all waves done reading K

        if (st + 1 < st1) {   // prefetch next tile under PV (K dead, V alt buffer)
            gl_lds16(Kg0 + (st + 1) * 4096, Kd0);
            gl_lds16(Kg1 + (st + 1) * 4096, Kd1);
            gl_lds16(Vg0 + (st + 1) * 64, Vsh[cur ^ 1] + (w * 2 + 0) * 512);
            gl_lds16(Vg1 + (st + 1) * 64, Vsh[cur ^ 1] + (w * 2 + 1) * 512);
        }

        // O^T += V^T P^T : wave w owns d-rows w*16..+16, all 64 q-cols
        #pragma unroll
        for (int ks = 0; ks < 2; ks++) {
            bf16x8 af = *(const bf16x8*)&Vsh[cur][(w * 16 + ln) * 64 + (((ks * 4 + q) ^ kswz) << 3)];
            #pragma unroll
            for (int nt = 0; nt < 4; nt++) {
                bf16x8 bfr = *(const bf16x8*)&Ps[(nt * 16 + ln) * PPAD + ks * 32 + q * 8];
                o_acc[nt] = __builtin_amdgcn_mfma_f32_16x16x32_bf16(af, bfr, o_acc[nt], 0, 0, 0);
            }
        }
        cur ^= 1;
    }

    #pragma unroll
    for (int m = 1; m < 16; m <<= 1)
        #pragma unroll
        for (int r = 0; r < 4; r++)
            den_reg[r] += __shfl_xor(den_reg[r], m, 64);
    size_t slot = (size_t)nh * NCHUNK + u;
    if (ln == 0)
        #pragma unroll
        for (int r = 0; r < 4; r++)
            pden[slot * 64 + w * 16 + q * 4 + r] = den_reg[r];

    #pragma unroll
    for (int nt = 0; nt < 4; nt++)
        *(f32x4*)&po[(slot << 12) + (size_t)(nt * 16 + ln) * 64 + w * 16 + q * 4] = o_acc[nt];
}

// ---------------- fused split-KV combine + residual + LayerNorm ----------------
__global__ __launch_bounds__(256) void add_ln_attn_kernel(float* __restrict__ h,
    __bf16* __restrict__ hb, const float* __restrict__ po, const float* __restrict__ pden,
    const float* __restrict__ g, const float* __restrict__ b)
{
    int w = threadIdx.x >> 6, lane = threadIdx.x & 63;
    int row = (blockIdx.x << 2) + w;          // n*1024 + t
    int n = row >> 10, t = row & (TT - 1);
    int qt = t >> 6, qrow = t & 63;
    int gg = qt >> 2, nc = gg + 1;
    const int offs[4] = {0, 4, 12, 24};
    int u0 = offs[gg] + (qt - gg * 4) * nc;
    int hh = lane >> 3;
    int d0 = (lane & 7) * 8;
    size_t s0 = (size_t)(n * NHD + hh) * NCHUNK + u0;

    f32x4 a0 = {0.f,0.f,0.f,0.f}, a1 = {0.f,0.f,0.f,0.f};
    float den = 0.f;
    for (int c = 0; c < nc; c++) {
        const float* p = po + ((s0 + c) << 12) + (size_t)qrow * 64 + d0;
        a0 += *(const f32x4*)p;
        a1 += *(const f32x4*)(p + 4);
        den += pden[(s0 + c) * 64 + qrow];
    }
    float inv = 1.0f / den;

    size_t base = (size_t)row * DM + lane * 8;
    f32x4 x0 = *(const f32x4*)&h[base];
    f32x4 x1 = *(const f32x4*)&h[base + 4];
    x0 += a0 * inv;
    x1 += a1 * inv;

    float s1 = x0[0]+x0[1]+x0[2]+x0[3] + x1[0]+x1[1]+x1[2]+x1[3];
    float s2 = x0[0]*x0[0]+x0[1]*x0[1]+x0[2]*x0[2]+x0[3]*x0[3]
             + x1[0]*x1[0]+x1[1]*x1[1]+x1[2]*x1[2]+x1[3]*x1[3];
    #pragma unroll
    for (int m = 1; m < 64; m <<= 1) {
        s1 += __shfl_xor(s1, m, 64);
        s2 += __shfl_xor(s2, m, 64);
    }
    float mean = s1 * (1.0f / 512.0f);
    float var = s2 * (1.0f / 512.0f) - mean * mean;
    float rstd = rsqrtf(var + 1e-3f);

    f32x4 gg0 = *(const f32x4*)&g[lane * 8];
    f32x4 gg1 = *(const f32x4*)&g[lane * 8 + 4];
    f32x4 bb0 = *(const f32x4*)&b[lane * 8];
    f32x4 bb1 = *(const f32x4*)&b[lane * 8 + 4];
    f32x4 o0, o1;
    bf16x8 pb;
    #pragma unroll
    for (int i = 0; i < 4; i++) {
        o0[i] = gg0[i] * ((x0[i] - mean) * rstd) + bb0[i];
        o1[i] = gg1[i] * ((x1[i] - mean) * rstd) + bb1[i];
        pb[i] = (__bf16)o0[i];
        pb[4 + i] = (__bf16)o1[i];
    }
    *(f32x4*)&h[base] = o0;
    *(f32x4*)&h[base + 4] = o1;
    *(bf16x8*)(hb + base) = pb;
}

// ---------------- residual add + LayerNorm (one wave per row) ----------------
__global__ __launch_bounds__(256) void add_ln_kernel(float* __restrict__ h,
    __bf16* __restrict__ hb, const float* __restrict__ a,
    const float* __restrict__ g, const float* __restrict__ b)
{
    int w = threadIdx.x >> 6, lane = threadIdx.x & 63;
    int row = (blockIdx.x << 2) + w;
    size_t base4 = (size_t)row * (DM / 4);
    const float4* h4 = (const float4*)h;
    const float4* a4 = (const float4*)a;
    float4 x0 = h4[base4 + lane];
    float4 x1 = h4[base4 + 64 + lane];
    float4 y0 = a4[base4 + lane];
    float4 y1 = a4[base4 + 64 + lane];
    x0.x += y0.x; x0.y += y0.y; x0.z += y0.z; x0.w += y0.w;
    x1.x += y1.x; x1.y += y1.y; x1.z += y1.z; x1.w += y1.w;
    float s1 = x0.x + x0.y + x0.z + x0.w + x1.x + x1.y + x1.z + x1.w;
    float s2 = x0.x*x0.x + x0.y*x0.y + x0.z*x0.z + x0.w*x0.w
             + x1.x*x1.x + x1.y*x1.y + x1.z*x1.z + x1.w*x1.w;
    #pragma unroll
    for (int m = 1; m < 64; m <<= 1) {
        s1 += __shfl_xor(s1, m, 64);
        s2 += __shfl_xor(s2, m, 64);
    }
    float mean = s1 * (1.0f / 512.0f);
    float var = s2 * (1.0f / 512.0f) - mean * mean;
    float rstd = rsqrtf(var + 1e-3f);
    const float4* g4 = (const float4*)g;
    const float4* b4 = (const float4*)b;
    float4 gg0 = g4[lane], gg1 = g4[64 + lane];
    float4 bb0 = b4[lane], bb1 = b4[64 + lane];
    float4 o0, o1;
    o0.x = gg0.x * ((x0.x - mean) * rstd) + bb0.x;
    o0.y = gg0.y * ((x0.y - mean) * rstd) + bb0.y;
    o0.z = gg0.z * ((x0.z - mean) * rstd) + bb0.z;
    o0.w = gg0.w * ((x0.w - mean) * rstd) + bb0.w;
    o1.x = gg1.x * ((x1.x - mean) * rstd) + bb1.x;
    o1.y = gg1.y * ((x1.y - mean) * rstd) + bb1.y;
    o1.z = gg1.z * ((x1.z - mean) * rstd) + bb1.z;
    o1.w = gg1.w * ((x1.w - mean) * rstd) + bb1.w;
    ((float4*)h)[base4 + lane] = o0;
    ((float4*)h)[base4 + 64 + lane] = o1;
    bf16x4 p0, p1;
    p0[0] = (__bf16)o0.x; p0[1] = (__bf16)o0.y; p0[2] = (__bf16)o0.z; p0[3] = (__bf16)o0.w;
    p1[0] = (__bf16)o1.x; p1[1] = (__bf16)o1.y; p1[2] = (__bf16)o1.z; p1[3] = (__bf16)o1.w;
    *(bf16x4*)(hb + (size_t)row * DM + lane * 4) = p0;
    *(bf16x4*)(hb + (size_t)row * DM + 256 + lane * 4) = p1;
}

extern "C" void kernel_launch(void* const* d_in, const int* in_sizes, int n_in,
                              void* d_out, int out_size, void* d_ws, size_t ws_size,
                              hipStream_t stream) {
    const int*   x     = (const int*)d_in[0];
    const float* emb   = (const float*)d_in[1];
    const float* Wqkv  = (const float*)d_in[2];
    const float* bqkv  = (const float*)d_in[3];
    const float* Wff   = (const float*)d_in[4];
    const float* bff   = (const float*)d_in[5];
    const float* Wo    = (const float*)d_in[6];
    const float* bo    = (const float*)d_in[7];
    const float* g1    = (const float*)d_in[8];
    const float* beta1 = (const float*)d_in[9];
    const float* g2    = (const float*)d_in[10];
    const float* beta2 = (const float*)d_in[11];

    float* h = (float*)d_out;               // [4096, 512] running hidden state
    char* w = (char*)d_ws;
    __bf16* qkvb = (__bf16*)w;                        // 12,582,912 B (Q|K|V^T bf16)
    __bf16* ffb  = (__bf16*)w;                        // aliases qkv (dead after attn)
    float*  abuf = (float*)(w + 25165824);            //  8,388,608 B (FF2 out)
    __bf16* hb   = (__bf16*)(w + 33554432);           //  4,194,304 B
    __bf16* WtQ  = (__bf16*)(w + 37748736);           //  9,437,184 B  [L][1536][512] (perm'd rows)
    __bf16* WtF  = (__bf16*)(w + 47185920);           //  6,291,456 B  [L][1024][512]
    __bf16* WtO  = (__bf16*)(w + 53477376);           //  6,291,456 B  [L][512][1024]
    float*  po   = (float*)(w + 59768832);            // 20,971,520 B  [32*40][64][64]
    float*  pden = (float*)(w + 80740352);            //    327,680 B  [32*40][64]
    float*  bqkv_p = (float*)(w + 81068032);          //     36,864 B  [L][1536] perm'd bias

    convert_all_kernel<<<dim3(1792, 1, LAYERS), 256, 0, stream>>>(
        Wqkv, Wff, Wo, bqkv, WtQ, WtF, WtO, bqkv_p);

    embed_pos_kernel<<<MROWS, 256, 0, stream>>>(x, emb, h, hb);

    for (int l = 0; l < LAYERS; l++) {
        const float* bff_l  = bff  + (size_t)l * DFFD;
        const float* bo_l   = bo   + (size_t)l * DM;

        // QKV projection (bf16 MFMA, permuted cols) -> bf16 Q,K [n,h,t,d] + V^T [n,h,d,t]
        gemm_mfma<<<dim3(12, 32), 256, 0, stream>>>(
            hb, WtQ + (size_t)l * 1536 * 512, bqkv_p + l * 1536, qkvb, MROWS, 3 * DM, DM, 2);

        attn_partial_kernel<<<dim3(NCHUNK, NB * NHD), 256, 0, stream>>>(
            qkvb, qkvb + PERBUF, qkvb + 2 * (size_t)PERBUF, po, pden);

        // fused: combine split-KV partials + residual + LN1
        add_ln_attn_kernel<<<MROWS / 4, 256, 0, stream>>>(
            h, hb, po, pden, g1 + l * DM, beta1 + l * DM);

        // FF1: relu(h @ Wff + bff) -> bf16
        gemm_mfma<<<dim3(8, 32), 256, 0, stream>>>(
            hb, WtF + (size_t)l * 1024 * 512, bff_l, ffb, MROWS, DFFD, DM, 1);

        // FF2: ff @ Wo + bo -> fp32 (128x64 tiles, 256 blocks)
        gemm_ff2<<<dim3(8, 32), 256, 0, stream>>>(
            ffb, WtO + (size_t)l * 512 * 1024, bo_l, abuf, MROWS, DM, DFFD);

        add_ln_kernel<<<MROWS / 4, 256, 0, stream>>>(h, hb, abuf, g2 + l * DM, beta2 + l * DM);
    }
}

// Round 5
// 638.811 us; speedup vs baseline: 1.2959x; 1.2959x over previous
//
#include <hip/hip_runtime.h>
#include <hip/hip_bf16.h>
#include <math.h>

#define DM   512
#define TT   1024
#define NB   4
#define NHD  8
#define LAYERS 6
#define DFFD 1024
#define MROWS (NB*TT)          // 4096
#define PERBUF (NB*NHD*TT*64)  // 2097152 elems per Q/K/V buffer

typedef __bf16 bf16x8 __attribute__((ext_vector_type(8)));
typedef __bf16 bf16x4 __attribute__((ext_vector_type(4)));
typedef float f32x4 __attribute__((ext_vector_type(4)));

// async global->LDS, 16B per lane; LDS base must be wave-uniform (m104/m108)
__device__ __forceinline__ void gl_lds16(const __bf16* g, __bf16* l) {
    __builtin_amdgcn_global_load_lds((const __attribute__((address_space(1))) void*)g,
                                     (__attribute__((address_space(3))) void*)l, 16, 0, 0);
}

// ---------------- embedding + positional encoding (fp32 h + bf16 shadow) ----------------
__global__ __launch_bounds__(256) void embed_pos_kernel(const int* __restrict__ x,
    const float* __restrict__ emb, float* __restrict__ h, __bf16* __restrict__ hb)
{
    int row = blockIdx.x;            // n*T + t
    int t = row & (TT - 1);
    int tok = x[row];
    const float* e = emb + (size_t)tok * DM;
    float* out = h + (size_t)row * DM;
    __bf16* outb = hb + (size_t)row * DM;
    for (int i = threadIdx.x; i < DM; i += 256) {
        float val = e[i] * 22.62741699796952f;   // sqrt(512)
        int pair = i >> 1;
        float rate = powf(10000.0f, -(float)pair * (1.0f / 256.0f));
        float ang = (float)t * rate;
        float pe = (i & 1) ? cosf(ang) : sinf(ang);
        float v = val + pe;
        out[i] = v;
        outb[i] = (__bf16)v;
    }
}

// ---------------- all-weight convert + transpose (one dispatch) ----------------
// W[K,N] fp32 -> Wt[N,K] bf16. For Wqkv, output columns are PERMUTED:
// original col c -> row (c%3)*512 + c/3, grouping Q|K|V with inner [h][d].
__global__ __launch_bounds__(256) void convert_all_kernel(
    const float* __restrict__ Wqkv, const float* __restrict__ Wff, const float* __restrict__ Wo,
    const float* __restrict__ bqkv,
    __bf16* __restrict__ WtQ, __bf16* __restrict__ WtF, __bf16* __restrict__ WtO,
    float* __restrict__ bqkv_p)
{
    __shared__ float tile[32][33];
    int l = blockIdx.z;
    int t = blockIdx.x;
    const float* W; __bf16* Wt; int K, N, bx, by; bool perm = false;
    if (t < 768)       { W = Wqkv; Wt = WtQ; K = 512;  N = 1536; bx = t & 15;  by = t >> 4; perm = true; }
    else if (t < 1280) { int u = t - 768;  W = Wff; Wt = WtF; K = 512;  N = 1024; bx = u & 15; by = u >> 4; }
    else               { int u = t - 1280; W = Wo;  Wt = WtO; K = 1024; N = 512;  bx = u & 31; by = u >> 5; }
    int k0 = bx * 32, n0 = by * 32;
    const float* Wl = W + (size_t)l * K * N;
    __bf16* Wtl = Wt + (size_t)l * K * N;
    int tx = threadIdx.x & 31, ty = threadIdx.x >> 5;   // ty 0..7
    #pragma unroll
    for (int i = ty; i < 32; i += 8)
        tile[i][tx] = Wl[(size_t)(k0 + i) * N + n0 + tx];
    if (perm && bx == 0 && ty == 0) {                   // permute bias once per col-chunk
        int c = n0 + tx;
        bqkv_p[l * 1536 + (c % 3) * 512 + c / 3] = bqkv[(size_t)l * 1536 + c];
    }
    __syncthreads();
    #pragma unroll
    for (int i = ty; i < 32; i += 8) {
        int c = n0 + i;
        int row = perm ? ((c % 3) * 512 + c / 3) : c;
        Wtl[(size_t)row * K + k0 + tx] = (__bf16)tile[tx][i];
    }
}

// ---------------- bf16 MFMA GEMM, templated tile, 2-phase pipelined 32-K panels ----------------
// Smaller tiles than before (128x64 / 64x64): grid 2-3 blocks/CU (vs 1-1.5), i.e.
// 2-3 waves/SIMD, so other waves run during each barrier's vmcnt drain. (R4 lesson:
// fragment loads MUST go via LDS staging — direct-global is stride-K uncoalesced.)
// MODE 0: fp32 C out (+bias). MODE 1: relu -> bf16. MODE 2: QKV scatter, PERMUTED cols:
// c in [0,512)=Q, [512,1024)=K (both [n,h,t,d]), [1024,1536)=V^T [n,h,d,t].
template<int BM, int BN, int MODE>
__global__ __launch_bounds__(256) void gemm2p(const __bf16* __restrict__ A,
    const __bf16* __restrict__ Bt, const float* __restrict__ bias,
    void* __restrict__ Cv, int M, int Nc, int K)
{
    constexpr int WM = BM / 2, WN = BN / 2;
    constexpr int MT = WM / 16, NT = WN / 16;
    constexpr int ACH = BM / 64;   // 16-row A chunks staged per wave
    constexpr int BCH = BN / 64;   // 16-row B chunks staged per wave
    __shared__ __align__(16) __bf16 As[2][BM * 32];
    __shared__ __align__(16) __bf16 Bs[2][BN * 32];
    int tid = threadIdx.x;
    int lane = tid & 63;
    int wave = tid >> 6;
    int ln = lane & 15, q = lane >> 4;
    int wrow = (wave >> 1) * WM, wcol = (wave & 1) * WN;
    int n0 = blockIdx.x * BN, m0 = blockIdx.y * BM;

    f32x4 acc[MT][NT] = {};

    const __bf16* Ab = A + (size_t)m0 * K;
    const __bf16* Bb = Bt + (size_t)n0 * K;
    int srow = lane >> 2;            // 0..15
    int scol = (lane & 3) * 8;       // bf16 elems: 0,8,16,24

    const __bf16* Aga[ACH];
    const __bf16* Bga[BCH];
    #pragma unroll
    for (int i = 0; i < ACH; i++)
        Aga[i] = Ab + (size_t)(wave * (16 * ACH) + 16 * i + srow) * K + scol;
    #pragma unroll
    for (int i = 0; i < BCH; i++)
        Bga[i] = Bb + (size_t)(wave * (16 * BCH) + 16 * i + srow) * K + scol;

    auto STAGE = [&](int kp, int buf) {
        #pragma unroll
        for (int i = 0; i < ACH; i++)
            gl_lds16(Aga[i] + kp, As[buf] + (wave * (16 * ACH) + 16 * i) * 32);
        #pragma unroll
        for (int i = 0; i < BCH; i++)
            gl_lds16(Bga[i] + kp, Bs[buf] + (wave * (16 * BCH) + 16 * i) * 32);
    };
    auto COMPUTE = [&](int buf) {
        bf16x8 af[MT], bfr[NT];
        #pragma unroll
        for (int mt = 0; mt < MT; mt++)
            af[mt] = *(const bf16x8*)&As[buf][(wrow + mt * 16 + ln) * 32 + q * 8];
        #pragma unroll
        for (int nt = 0; nt < NT; nt++)
            bfr[nt] = *(const bf16x8*)&Bs[buf][(wcol + nt * 16 + ln) * 32 + q * 8];
        #pragma unroll
        for (int mt = 0; mt < MT; mt++)
            #pragma unroll
            for (int nt = 0; nt < NT; nt++)
                acc[mt][nt] = __builtin_amdgcn_mfma_f32_16x16x32_bf16(af[mt], bfr[nt], acc[mt][nt], 0, 0, 0);
    };

    STAGE(0, 0);
    __syncthreads();
    int kp = 0;
    for (; kp + 64 < K; kp += 64) {
        STAGE(kp + 32, 1);
        COMPUTE(0);
        __syncthreads();      // drain: panel kp+32 landed; buf0 readers done
        STAGE(kp + 64, 0);
        COMPUTE(1);
        __syncthreads();      // drain: panel kp+64 landed; buf1 readers done
    }
    STAGE(kp + 32, 1);
    COMPUTE(0);
    __syncthreads();
    COMPUTE(1);

    #pragma unroll
    for (int mt = 0; mt < MT; mt++) {
        int mbase = m0 + wrow + mt * 16 + q * 4;
        if constexpr (MODE == 0) {
            float* C = (float*)Cv;
            #pragma unroll
            for (int r = 0; r < 4; r++) {
                int m = mbase + r;
                #pragma unroll
                for (int nt = 0; nt < NT; nt++) {
                    int c = n0 + wcol + nt * 16 + ln;
                    C[(size_t)m * Nc + c] = acc[mt][nt][r] + bias[c];
                }
            }
        } else if constexpr (MODE == 1) {
            __bf16* Cb = (__bf16*)Cv;
            #pragma unroll
            for (int r = 0; r < 4; r++) {
                int m = mbase + r;
                #pragma unroll
                for (int nt = 0; nt < NT; nt++) {
                    int c = n0 + wcol + nt * 16 + ln;
                    float val = acc[mt][nt][r] + bias[c];
                    Cb[(size_t)m * Nc + c] = (__bf16)fmaxf(val, 0.f);
                }
            }
        } else {
            __bf16* Cb = (__bf16*)Cv;
            int n = mbase >> 10, t = mbase & (TT - 1);
            #pragma unroll
            for (int nt = 0; nt < NT; nt++) {
                int c = n0 + wcol + nt * 16 + ln;
                int buf = c >> 9;            // uniform within the 16-col group
                int hd = c & 511;
                int hh = hd >> 6, d = hd & 63;
                float bv = bias[c];
                if (buf == 2) {              // V^T [n,h,d,t]: 4 consecutive t -> one 8B store
                    size_t idx = 2 * (size_t)PERBUF + (((size_t)(n * NHD + hh) * 64 + d) << 10) + t;
                    bf16x4 v4;
                    #pragma unroll
                    for (int r = 0; r < 4; r++) v4[r] = (__bf16)(acc[mt][nt][r] + bv);
                    *(bf16x4*)&Cb[idx] = v4;
                } else {                     // Q,K [n,h,t,d]
                    size_t base = (size_t)buf * PERBUF + (((size_t)(n * NHD + hh) * TT + t) << 6) + d;
                    #pragma unroll
                    for (int r = 0; r < 4; r++)
                        Cb[base + (size_t)(r << 6)] = (__bf16)(acc[mt][nt][r] + bv);
                }
            }
        }
    }
}

// ---------------- split-KV MFMA flash attention ----------------
// Q fragments in registers. K single-buffered + V double-buffered in LDS via
// async global_load_lds with XOR-swizzled source (linear dest, swizzled read).
// QK^T computed SWAPPED (S^T = K Q^T): C-layout puts 4 consecutive s per lane for
// one q-row, so the P store is 4x bf16x4 (was 16x ds_write_b16) and the den
// reduction is 2 shuffles (was 4 chains). PV unchanged. 2 barriers per KV tile.
#define PPAD 72
#define NCHUNK 40
__global__ __launch_bounds__(256) void attn_partial_kernel(const __bf16* __restrict__ qb,
    const __bf16* __restrict__ kb, const __bf16* __restrict__ vtb,
    float* __restrict__ po, float* __restrict__ pden)
{
    __shared__ __align__(16) __bf16 Ksh[64 * 64];      // K tile [s][d], swizzled
    __shared__ __align__(16) __bf16 Vsh[2][64 * 64];   // V^T tile [d][s], swizzled
    __shared__ __align__(16) __bf16 Ps[64 * PPAD];     // P tile [q][s], padded

    int u = (NCHUNK - 1) - blockIdx.x;   // heavy chunks dispatch first
    int nh = blockIdx.y;
    int g, off;
    if (u < 4)       { g = 0; off = 0;  }
    else if (u < 12) { g = 1; off = 4;  }
    else if (u < 24) { g = 2; off = 12; }
    else             { g = 3; off = 24; }
    int rem = u - off;
    int nper = g + 1;
    int qq = rem / nper;           // 0..3
    int c  = rem - qq * nper;
    int qt = g * 4 + qq;
    int st0 = c * 4;
    int st1 = min(st0 + 4, qt + 1);

    int tid = threadIdx.x;
    int lane = tid & 63, w = tid >> 6;
    int ln = lane & 15, q = lane >> 4;

    const __bf16* Kg = kb + (size_t)nh * TT * 64;
    const __bf16* Vg = vtb + (size_t)nh * 64 * TT;   // [d][t]

    // Q fragments in registers: wave w owns q-rows w*16..+16 of this q-tile
    const __bf16* Qrow = qb + ((size_t)nh * TT + (size_t)qt * 64 + w * 16 + ln) * 64;
    bf16x8 aq0 = *(const bf16x8*)(Qrow + q * 8);
    bf16x8 aq1 = *(const bf16x8*)(Qrow + 32 + q * 8);

    // staging geometry: wave w issue i covers LDS bytes [(w*2+i)*1024, +1024)
    // lane l -> row (w*2+i)*8 + (l>>3), col16 l&7; source col pre-swizzled.
    int srow = lane >> 3;                        // 0..7  == (row & 7)
    int swz  = ((lane & 7) ^ srow) << 3;         // swizzled source col (elems)
    int r0 = (w * 2 + 0) * 8 + srow;
    int r1 = (w * 2 + 1) * 8 + srow;
    const __bf16* Kg0 = Kg + (size_t)r0 * 64 + swz;
    const __bf16* Kg1 = Kg + (size_t)r1 * 64 + swz;
    const __bf16* Vg0 = Vg + (size_t)r0 * TT + swz;
    const __bf16* Vg1 = Vg + (size_t)r1 * TT + swz;
    __bf16* Kd0 = Ksh + (w * 2 + 0) * 512;
    __bf16* Kd1 = Ksh + (w * 2 + 1) * 512;

    f32x4 o_acc[4] = {};
    float den_lane = 0.f;          // partial softmax denom for q-row w*16+ln
    int qrow_l = w * 16 + ln;

    int cur = 0;
    gl_lds16(Kg0 + st0 * 4096, Kd0);
    gl_lds16(Kg1 + st0 * 4096, Kd1);
    gl_lds16(Vg0 + st0 * 64, Vsh[0] + (w * 2 + 0) * 512);
    gl_lds16(Vg1 + st0 * 64, Vsh[0] + (w * 2 + 1) * 512);

    int kswz = ln & 7;   // row&7 for all swizzled reads below (rows stride 16)
    for (int st = st0; st < st1; st++) {
        __syncthreads();   // staged K/V landed (vmcnt drain); prior P/V readers done

        // S^T = K Q^T: wave w computes S^T[all 64 s][its 16 q-cols]
        f32x4 st_acc[4] = {};
        #pragma unroll
        for (int mt = 0; mt < 4; mt++) {
            int r = mt * 16 + ln;
            bf16x8 k0v = *(const bf16x8*)&Ksh[r * 64 + ((q ^ kswz) << 3)];
            st_acc[mt] = __builtin_amdgcn_mfma_f32_16x16x32_bf16(k0v, aq0, st_acc[mt], 0, 0, 0);
            bf16x8 k1v = *(const bf16x8*)&Ksh[r * 64 + (((q + 4) ^ kswz) << 3)];
            st_acc[mt] = __builtin_amdgcn_mfma_f32_16x16x32_bf16(k1v, aq1, st_acc[mt], 0, 0, 0);
        }

        // P = exp(S/8), causal mask on diagonal tile. Lane holds 4 consecutive s
        // (mt*16 + q*4 + r) for its q-row -> one bf16x4 store per mt.
        bool diag = (st == qt);
        #pragma unroll
        for (int mt = 0; mt < 4; mt++) {
            int s0i = mt * 16 + q * 4;
            bf16x4 p4;
            #pragma unroll
            for (int r = 0; r < 4; r++) {
                float p;
                if (diag && (s0i + r) > qrow_l) p = 0.f;
                else p = exp2f(st_acc[mt][r] * 0.18033688011112042f);  // /8 * log2(e)
                den_lane += p;
                p4[r] = (__bf16)p;
            }
            *(bf16x4*)&Ps[qrow_l * PPAD + s0i] = p4;
        }
        __syncthreads();   // P visible; all waves done reading K

        if (st + 1 < st1) {   // prefetch next tile under PV (K dead, V alt buffer)
            gl_lds16(Kg0 + (st + 1) * 4096, Kd0);
            gl_lds16(Kg1 + (st + 1) * 4096, Kd1);
            gl_lds16(Vg0 + (st + 1) * 64, Vsh[cur ^ 1] + (w * 2 + 0) * 512);
            gl_lds16(Vg1 + (st + 1) * 64, Vsh[cur ^ 1] + (w * 2 + 1) * 512);
        }

        // O^T += V^T P^T : wave w owns d-rows w*16..+16, all 64 q-cols
        #pragma unroll
        for (int ks = 0; ks < 2; ks++) {
            bf16x8 af = *(const bf16x8*)&Vsh[cur][(w * 16 + ln) * 64 + (((ks * 4 + q) ^ kswz) << 3)];
            #pragma unroll
            for (int nt = 0; nt < 4; nt++) {
                bf16x8 bfr = *(const bf16x8*)&Ps[(nt * 16 + ln) * PPAD + ks * 32 + q * 8];
                o_acc[nt] = __builtin_amdgcn_mfma_f32_16x16x32_bf16(af, bfr, o_acc[nt], 0, 0, 0);
            }
        }
        cur ^= 1;
    }

    // den: lanes {ln, ln+16, ln+32, ln+48} hold s-partitions of q-row w*16+ln
    den_lane += __shfl_xor(den_lane, 16, 64);
    den_lane += __shfl_xor(den_lane, 32, 64);
    size_t slot = (size_t)nh * NCHUNK + u;
    if (lane < 16)
        pden[slot * 64 + qrow_l] = den_lane;

    #pragma unroll
    for (int nt = 0; nt < 4; nt++)
        *(f32x4*)&po[(slot << 12) + (size_t)(nt * 16 + ln) * 64 + w * 16 + q * 4] = o_acc[nt];
}

// ---------------- fused split-KV combine + residual + LayerNorm ----------------
__global__ __launch_bounds__(256) void add_ln_attn_kernel(float* __restrict__ h,
    __bf16* __restrict__ hb, const float* __restrict__ po, const float* __restrict__ pden,
    const float* __restrict__ g, const float* __restrict__ b)
{
    int w = threadIdx.x >> 6, lane = threadIdx.x & 63;
    int row = (blockIdx.x << 2) + w;          // n*1024 + t
    int n = row >> 10, t = row & (TT - 1);
    int qt = t >> 6, qrow = t & 63;
    int gg = qt >> 2, nc = gg + 1;
    const int offs[4] = {0, 4, 12, 24};
    int u0 = offs[gg] + (qt - gg * 4) * nc;
    int hh = lane >> 3;
    int d0 = (lane & 7) * 8;
    size_t s0 = (size_t)(n * NHD + hh) * NCHUNK + u0;

    f32x4 a0 = {0.f,0.f,0.f,0.f}, a1 = {0.f,0.f,0.f,0.f};
    float den = 0.f;
    for (int c = 0; c < nc; c++) {
        const float* p = po + ((s0 + c) << 12) + (size_t)qrow * 64 + d0;
        a0 += *(const f32x4*)p;
        a1 += *(const f32x4*)(p + 4);
        den += pden[(s0 + c) * 64 + qrow];
    }
    float inv = 1.0f / den;

    size_t base = (size_t)row * DM + lane * 8;
    f32x4 x0 = *(const f32x4*)&h[base];
    f32x4 x1 = *(const f32x4*)&h[base + 4];
    x0 += a0 * inv;
    x1 += a1 * inv;

    float s1 = x0[0]+x0[1]+x0[2]+x0[3] + x1[0]+x1[1]+x1[2]+x1[3];
    float s2 = x0[0]*x0[0]+x0[1]*x0[1]+x0[2]*x0[2]+x0[3]*x0[3]
             + x1[0]*x1[0]+x1[1]*x1[1]+x1[2]*x1[2]+x1[3]*x1[3];
    #pragma unroll
    for (int m = 1; m < 64; m <<= 1) {
        s1 += __shfl_xor(s1, m, 64);
        s2 += __shfl_xor(s2, m, 64);
    }
    float mean = s1 * (1.0f / 512.0f);
    float var = s2 * (1.0f / 512.0f) - mean * mean;
    float rstd = rsqrtf(var + 1e-3f);

    f32x4 gg0 = *(const f32x4*)&g[lane * 8];
    f32x4 gg1 = *(const f32x4*)&g[lane * 8 + 4];
    f32x4 bb0 = *(const f32x4*)&b[lane * 8];
    f32x4 bb1 = *(const f32x4*)&b[lane * 8 + 4];
    f32x4 o0, o1;
    bf16x8 pb;
    #pragma unroll
    for (int i = 0; i < 4; i++) {
        o0[i] = gg0[i] * ((x0[i] - mean) * rstd) + bb0[i];
        o1[i] = gg1[i] * ((x1[i] - mean) * rstd) + bb1[i];
        pb[i] = (__bf16)o0[i];
        pb[4 + i] = (__bf16)o1[i];
    }
    *(f32x4*)&h[base] = o0;
    *(f32x4*)&h[base + 4] = o1;
    *(bf16x8*)(hb + base) = pb;
}

// ---------------- residual add + LayerNorm (one wave per row) ----------------
__global__ __launch_bounds__(256) void add_ln_kernel(float* __restrict__ h,
    __bf16* __restrict__ hb, const float* __restrict__ a,
    const float* __restrict__ g, const float* __restrict__ b)
{
    int w = threadIdx.x >> 6, lane = threadIdx.x & 63;
    int row = (blockIdx.x << 2) + w;
    size_t base4 = (size_t)row * (DM / 4);
    const float4* h4 = (const float4*)h;
    const float4* a4 = (const float4*)a;
    float4 x0 = h4[base4 + lane];
    float4 x1 = h4[base4 + 64 + lane];
    float4 y0 = a4[base4 + lane];
    float4 y1 = a4[base4 + 64 + lane];
    x0.x += y0.x; x0.y += y0.y; x0.z += y0.z; x0.w += y0.w;
    x1.x += y1.x; x1.y += y1.y; x1.z += y1.z; x1.w += y1.w;
    float s1 = x0.x + x0.y + x0.z + x0.w + x1.x + x1.y + x1.z + x1.w;
    float s2 = x0.x*x0.x + x0.y*x0.y + x0.z*x0.z + x0.w*x0.w
             + x1.x*x1.x + x1.y*x1.y + x1.z*x1.z + x1.w*x1.w;
    #pragma unroll
    for (int m = 1; m < 64; m <<= 1) {
        s1 += __shfl_xor(s1, m, 64);
        s2 += __shfl_xor(s2, m, 64);
    }
    float mean = s1 * (1.0f / 512.0f);
    float var = s2 * (1.0f / 512.0f) - mean * mean;
    float rstd = rsqrtf(var + 1e-3f);
    const float4* g4 = (const float4*)g;
    const float4* b4 = (const float4*)b;
    float4 gg0 = g4[lane], gg1 = g4[64 + lane];
    float4 bb0 = b4[lane], bb1 = b4[64 + lane];
    float4 o0, o1;
    o0.x = gg0.x * ((x0.x - mean) * rstd) + bb0.x;
    o0.y = gg0.y * ((x0.y - mean) * rstd) + bb0.y;
    o0.z = gg0.z * ((x0.z - mean) * rstd) + bb0.z;
    o0.w = gg0.w * ((x0.w - mean) * rstd) + bb0.w;
    o1.x = gg1.x * ((x1.x - mean) * rstd) + bb1.x;
    o1.y = gg1.y * ((x1.y - mean) * rstd) + bb1.y;
    o1.z = gg1.z * ((x1.z - mean) * rstd) + bb1.z;
    o1.w = gg1.w * ((x1.w - mean) * rstd) + bb1.w;
    ((float4*)h)[base4 + lane] = o0;
    ((float4*)h)[base4 + 64 + lane] = o1;
    bf16x4 p0, p1;
    p0[0] = (__bf16)o0.x; p0[1] = (__bf16)o0.y; p0[2] = (__bf16)o0.z; p0[3] = (__bf16)o0.w;
    p1[0] = (__bf16)o1.x; p1[1] = (__bf16)o1.y; p1[2] = (__bf16)o1.z; p1[3] = (__bf16)o1.w;
    *(bf16x4*)(hb + (size_t)row * DM + lane * 4) = p0;
    *(bf16x4*)(hb + (size_t)row * DM + 256 + lane * 4) = p1;
}

extern "C" void kernel_launch(void* const* d_in, const int* in_sizes, int n_in,
                              void* d_out, int out_size, void* d_ws, size_t ws_size,
                              hipStream_t stream) {
    const int*   x     = (const int*)d_in[0];
    const float* emb   = (const float*)d_in[1];
    const float* Wqkv  = (const float*)d_in[2];
    const float* bqkv  = (const float*)d_in[3];
    const float* Wff   = (const float*)d_in[4];
    const float* bff   = (const float*)d_in[5];
    const float* Wo    = (const float*)d_in[6];
    const float* bo    = (const float*)d_in[7];
    const float* g1    = (const float*)d_in[8];
    const float* beta1 = (const float*)d_in[9];
    const float* g2    = (const float*)d_in[10];
    const float* beta2 = (const float*)d_in[11];

    float* h = (float*)d_out;               // [4096, 512] running hidden state
    char* w = (char*)d_ws;
    __bf16* qkvb = (__bf16*)w;                        // 12,582,912 B (Q|K|V^T bf16)
    __bf16* ffb  = (__bf16*)w;                        // aliases qkv (dead after attn)
    float*  abuf = (float*)(w + 25165824);            //  8,388,608 B (FF2 out)
    __bf16* hb   = (__bf16*)(w + 33554432);           //  4,194,304 B
    __bf16* WtQ  = (__bf16*)(w + 37748736);           //  9,437,184 B  [L][1536][512] (perm'd rows)
    __bf16* WtF  = (__bf16*)(w + 47185920);           //  6,291,456 B  [L][1024][512]
    __bf16* WtO  = (__bf16*)(w + 53477376);           //  6,291,456 B  [L][512][1024]
    float*  po   = (float*)(w + 59768832);            // 20,971,520 B  [32*40][64][64]
    float*  pden = (float*)(w + 80740352);            //    327,680 B  [32*40][64]
    float*  bqkv_p = (float*)(w + 81068032);          //     36,864 B  [L][1536] perm'd bias

    convert_all_kernel<<<dim3(1792, 1, LAYERS), 256, 0, stream>>>(
        Wqkv, Wff, Wo, bqkv, WtQ, WtF, WtO, bqkv_p);

    embed_pos_kernel<<<MROWS, 256, 0, stream>>>(x, emb, h, hb);

    for (int l = 0; l < LAYERS; l++) {
        const float* bff_l  = bff  + (size_t)l * DFFD;
        const float* bo_l   = bo   + (size_t)l * DM;

        // QKV projection: 128x64 tiles -> 768 blocks (3/CU)
        gemm2p<128, 64, 2><<<dim3(24, 32), 256, 0, stream>>>(
            hb, WtQ + (size_t)l * 1536 * 512, bqkv_p + l * 1536, qkvb, MROWS, 3 * DM, 512);

        attn_partial_kernel<<<dim3(NCHUNK, NB * NHD), 256, 0, stream>>>(
            qkvb, qkvb + PERBUF, qkvb + 2 * (size_t)PERBUF, po, pden);

        // fused: combine split-KV partials + residual + LN1
        add_ln_attn_kernel<<<MROWS / 4, 256, 0, stream>>>(
            h, hb, po, pden, g1 + l * DM, beta1 + l * DM);

        // FF1: relu(h @ Wff + bff) -> bf16; 128x64 tiles -> 512 blocks (2/CU)
        gemm2p<128, 64, 1><<<dim3(16, 32), 256, 0, stream>>>(
            hb, WtF + (size_t)l * 1024 * 512, bff_l, ffb, MROWS, DFFD, 512);

        // FF2: ff @ Wo + bo -> fp32; 64x64 tiles -> 512 blocks (2/CU)
        gemm2p<64, 64, 0><<<dim3(8, 64), 256, 0, stream>>>(
            ffb, WtO + (size_t)l * 512 * 1024, bo_l, abuf, MROWS, DM, 1024);

        add_ln_kernel<<<MROWS / 4, 256, 0, stream>>>(h, hb, abuf, g2 + l * DM, beta2 + l * DM);
    }
}

// Round 6
// 631.419 us; speedup vs baseline: 1.3111x; 1.0117x over previous
//
#include <hip/hip_runtime.h>
#include <hip/hip_bf16.h>
#include <math.h>

#define DM   512
#define TT   1024
#define NB   4
#define NHD  8
#define LAYERS 6
#define DFFD 1024
#define MROWS (NB*TT)          // 4096
#define PERBUF (NB*NHD*TT*64)  // 2097152 elems per Q/K/V buffer

typedef __bf16 bf16x8 __attribute__((ext_vector_type(8)));
typedef __bf16 bf16x4 __attribute__((ext_vector_type(4)));
typedef float f32x4 __attribute__((ext_vector_type(4)));

// async global->LDS, 16B per lane; LDS base must be wave-uniform (m104/m108)
__device__ __forceinline__ void gl_lds16(const __bf16* g, __bf16* l) {
    __builtin_amdgcn_global_load_lds((const __attribute__((address_space(1))) void*)g,
                                     (__attribute__((address_space(3))) void*)l, 16, 0, 0);
}

// split-KV chunk tables (NCHUNK=24): qt 0-7 one chunk, qt 8-15 two chunks.
// Ordered heavy-first (u=0 dispatched first carries longest chains).
__constant__ signed char C_QT[24]  = {15,15,14, 7,14,13,13,12, 6,12,11,11,10, 5,10, 9, 9, 8, 4, 8, 3, 2, 1, 0};
__constant__ signed char C_ST0[24] = { 0, 8, 0, 0, 8, 0, 7, 0, 0, 7, 0, 6, 0, 0, 6, 0, 5, 0, 0, 5, 0, 0, 0, 0};
__constant__ signed char C_ST1[24] = { 8,16, 8, 8,15, 7,14, 7, 7,13, 6,12, 6, 6,11, 5,10, 5, 5, 9, 4, 3, 2, 1};
// combine: qt -> chunk ids (second valid only for qt>=8)
__constant__ unsigned char C_UA[16] = {23,22,21,20,18,13,8,3,17,15,12,10,7,5,2,0};
__constant__ unsigned char C_UB[16] = { 0, 0, 0, 0, 0, 0,0,0,19,16,14,11,9,6,4,1};
#define NCHUNK 24

// ---------------- embedding + positional encoding (fp32 h + bf16 shadow) ----------------
__global__ __launch_bounds__(256) void embed_pos_kernel(const int* __restrict__ x,
    const float* __restrict__ emb, float* __restrict__ h, __bf16* __restrict__ hb)
{
    int row = blockIdx.x;            // n*T + t
    int t = row & (TT - 1);
    int tok = x[row];
    const float* e = emb + (size_t)tok * DM;
    float* out = h + (size_t)row * DM;
    __bf16* outb = hb + (size_t)row * DM;
    for (int i = threadIdx.x; i < DM; i += 256) {
        float val = e[i] * 22.62741699796952f;   // sqrt(512)
        int pair = i >> 1;
        float rate = powf(10000.0f, -(float)pair * (1.0f / 256.0f));
        float ang = (float)t * rate;
        float pe = (i & 1) ? cosf(ang) : sinf(ang);
        float v = val + pe;
        out[i] = v;
        outb[i] = (__bf16)v;
    }
}

// ---------------- all-weight convert + transpose (one dispatch) ----------------
// W[K,N] fp32 -> Wt[N,K] bf16. For Wqkv, output columns are PERMUTED:
// original col c -> row (c%3)*512 + c/3, grouping Q|K|V with inner [h][d].
__global__ __launch_bounds__(256) void convert_all_kernel(
    const float* __restrict__ Wqkv, const float* __restrict__ Wff, const float* __restrict__ Wo,
    const float* __restrict__ bqkv,
    __bf16* __restrict__ WtQ, __bf16* __restrict__ WtF, __bf16* __restrict__ WtO,
    float* __restrict__ bqkv_p)
{
    __shared__ float tile[32][33];
    int l = blockIdx.z;
    int t = blockIdx.x;
    const float* W; __bf16* Wt; int K, N, bx, by; bool perm = false;
    if (t < 768)       { W = Wqkv; Wt = WtQ; K = 512;  N = 1536; bx = t & 15;  by = t >> 4; perm = true; }
    else if (t < 1280) { int u = t - 768;  W = Wff; Wt = WtF; K = 512;  N = 1024; bx = u & 15; by = u >> 4; }
    else               { int u = t - 1280; W = Wo;  Wt = WtO; K = 1024; N = 512;  bx = u & 31; by = u >> 5; }
    int k0 = bx * 32, n0 = by * 32;
    const float* Wl = W + (size_t)l * K * N;
    __bf16* Wtl = Wt + (size_t)l * K * N;
    int tx = threadIdx.x & 31, ty = threadIdx.x >> 5;   // ty 0..7
    #pragma unroll
    for (int i = ty; i < 32; i += 8)
        tile[i][tx] = Wl[(size_t)(k0 + i) * N + n0 + tx];
    if (perm && bx == 0 && ty == 0) {                   // permute bias once per col-chunk
        int c = n0 + tx;
        bqkv_p[l * 1536 + (c % 3) * 512 + c / 3] = bqkv[(size_t)l * 1536 + c];
    }
    __syncthreads();
    #pragma unroll
    for (int i = ty; i < 32; i += 8) {
        int c = n0 + i;
        int row = perm ? ((c % 3) * 512 + c / 3) : c;
        Wtl[(size_t)row * K + k0 + tx] = (__bf16)tile[tx][i];
    }
}

// ---------------- bf16 MFMA GEMM, templated tile, 2-phase pipelined 32-K panels ----------------
// Small tiles keep 2-3 blocks/CU so co-resident waves hide the barrier drains.
// MODE 0: fp32 C out (+bias). MODE 1: relu -> bf16. MODE 2: QKV scatter, PERMUTED cols:
// c in [0,512)=Q, [512,1024)=K (both [n,h,t,d]), [1024,1536)=V^T [n,h,d,t].
template<int BM, int BN, int MODE>
__global__ __launch_bounds__(256) void gemm2p(const __bf16* __restrict__ A,
    const __bf16* __restrict__ Bt, const float* __restrict__ bias,
    void* __restrict__ Cv, int M, int Nc, int K)
{
    constexpr int WM = BM / 2, WN = BN / 2;
    constexpr int MT = WM / 16, NT = WN / 16;
    constexpr int ACH = BM / 64;   // 16-row A chunks staged per wave
    constexpr int BCH = BN / 64;   // 16-row B chunks staged per wave
    __shared__ __align__(16) __bf16 As[2][BM * 32];
    __shared__ __align__(16) __bf16 Bs[2][BN * 32];
    int tid = threadIdx.x;
    int lane = tid & 63;
    int wave = tid >> 6;
    int ln = lane & 15, q = lane >> 4;
    int wrow = (wave >> 1) * WM, wcol = (wave & 1) * WN;
    int n0 = blockIdx.x * BN, m0 = blockIdx.y * BM;

    f32x4 acc[MT][NT] = {};

    const __bf16* Ab = A + (size_t)m0 * K;
    const __bf16* Bb = Bt + (size_t)n0 * K;
    int srow = lane >> 2;            // 0..15
    int scol = (lane & 3) * 8;       // bf16 elems: 0,8,16,24

    const __bf16* Aga[ACH];
    const __bf16* Bga[BCH];
    #pragma unroll
    for (int i = 0; i < ACH; i++)
        Aga[i] = Ab + (size_t)(wave * (16 * ACH) + 16 * i + srow) * K + scol;
    #pragma unroll
    for (int i = 0; i < BCH; i++)
        Bga[i] = Bb + (size_t)(wave * (16 * BCH) + 16 * i + srow) * K + scol;

    auto STAGE = [&](int kp, int buf) {
        #pragma unroll
        for (int i = 0; i < ACH; i++)
            gl_lds16(Aga[i] + kp, As[buf] + (wave * (16 * ACH) + 16 * i) * 32);
        #pragma unroll
        for (int i = 0; i < BCH; i++)
            gl_lds16(Bga[i] + kp, Bs[buf] + (wave * (16 * BCH) + 16 * i) * 32);
    };
    auto COMPUTE = [&](int buf) {
        bf16x8 af[MT], bfr[NT];
        #pragma unroll
        for (int mt = 0; mt < MT; mt++)
            af[mt] = *(const bf16x8*)&As[buf][(wrow + mt * 16 + ln) * 32 + q * 8];
        #pragma unroll
        for (int nt = 0; nt < NT; nt++)
            bfr[nt] = *(const bf16x8*)&Bs[buf][(wcol + nt * 16 + ln) * 32 + q * 8];
        #pragma unroll
        for (int mt = 0; mt < MT; mt++)
            #pragma unroll
            for (int nt = 0; nt < NT; nt++)
                acc[mt][nt] = __builtin_amdgcn_mfma_f32_16x16x32_bf16(af[mt], bfr[nt], acc[mt][nt], 0, 0, 0);
    };

    STAGE(0, 0);
    __syncthreads();
    int kp = 0;
    for (; kp + 64 < K; kp += 64) {
        STAGE(kp + 32, 1);
        COMPUTE(0);
        __syncthreads();      // drain: panel kp+32 landed; buf0 readers done
        STAGE(kp + 64, 0);
        COMPUTE(1);
        __syncthreads();      // drain: panel kp+64 landed; buf1 readers done
    }
    STAGE(kp + 32, 1);
    COMPUTE(0);
    __syncthreads();
    COMPUTE(1);

    #pragma unroll
    for (int mt = 0; mt < MT; mt++) {
        int mbase = m0 + wrow + mt * 16 + q * 4;
        if constexpr (MODE == 0) {
            float* C = (float*)Cv;
            #pragma unroll
            for (int r = 0; r < 4; r++) {
                int m = mbase + r;
                #pragma unroll
                for (int nt = 0; nt < NT; nt++) {
                    int c = n0 + wcol + nt * 16 + ln;
                    C[(size_t)m * Nc + c] = acc[mt][nt][r] + bias[c];
                }
            }
        } else if constexpr (MODE == 1) {
            __bf16* Cb = (__bf16*)Cv;
            #pragma unroll
            for (int r = 0; r < 4; r++) {
                int m = mbase + r;
                #pragma unroll
                for (int nt = 0; nt < NT; nt++) {
                    int c = n0 + wcol + nt * 16 + ln;
                    float val = acc[mt][nt][r] + bias[c];
                    Cb[(size_t)m * Nc + c] = (__bf16)fmaxf(val, 0.f);
                }
            }
        } else {
            __bf16* Cb = (__bf16*)Cv;
            int n = mbase >> 10, t = mbase & (TT - 1);
            #pragma unroll
            for (int nt = 0; nt < NT; nt++) {
                int c = n0 + wcol + nt * 16 + ln;
                int buf = c >> 9;            // uniform within the 16-col group
                int hd = c & 511;
                int hh = hd >> 6, d = hd & 63;
                float bv = bias[c];
                if (buf == 2) {              // V^T [n,h,d,t]: 4 consecutive t -> one 8B store
                    size_t idx = 2 * (size_t)PERBUF + (((size_t)(n * NHD + hh) * 64 + d) << 10) + t;
                    bf16x4 v4;
                    #pragma unroll
                    for (int r = 0; r < 4; r++) v4[r] = (__bf16)(acc[mt][nt][r] + bv);
                    *(bf16x4*)&Cb[idx] = v4;
                } else {                     // Q,K [n,h,t,d]
                    size_t base = (size_t)buf * PERBUF + (((size_t)(n * NHD + hh) * TT + t) << 6) + d;
                    #pragma unroll
                    for (int r = 0; r < 4; r++)
                        Cb[base + (size_t)(r << 6)] = (__bf16)(acc[mt][nt][r] + bv);
                }
            }
        }
    }
}

// ---------------- split-KV MFMA flash attention (NCHUNK=24, table-driven) ----------------
// Q fragments in registers. K single-buffered + V double-buffered in LDS via
// async global_load_lds with XOR-swizzled source (linear dest, swizzled read).
// QK^T computed SWAPPED (S^T = K Q^T): lane holds 4 consecutive s per q-row ->
// P store is 4x bf16x4, den reduction 2 shuffles. 768 blocks (3/CU), chains <= 8.
#define PPAD 72
__global__ __launch_bounds__(256) void attn_partial_kernel(const __bf16* __restrict__ qb,
    const __bf16* __restrict__ kb, const __bf16* __restrict__ vtb,
    float* __restrict__ po, float* __restrict__ pden)
{
    __shared__ __align__(16) __bf16 Ksh[64 * 64];      // K tile [s][d], swizzled
    __shared__ __align__(16) __bf16 Vsh[2][64 * 64];   // V^T tile [d][s], swizzled
    __shared__ __align__(16) __bf16 Ps[64 * PPAD];     // P tile [q][s], padded

    int u = blockIdx.x;                  // heavy chunks at low u (dispatch first)
    int nh = blockIdx.y;
    int qt  = C_QT[u];
    int st0 = C_ST0[u];
    int st1 = C_ST1[u];

    int tid = threadIdx.x;
    int lane = tid & 63, w = tid >> 6;
    int ln = lane & 15, q = lane >> 4;

    const __bf16* Kg = kb + (size_t)nh * TT * 64;
    const __bf16* Vg = vtb + (size_t)nh * 64 * TT;   // [d][t]

    // Q fragments in registers: wave w owns q-rows w*16..+16 of this q-tile
    const __bf16* Qrow = qb + ((size_t)nh * TT + (size_t)qt * 64 + w * 16 + ln) * 64;
    bf16x8 aq0 = *(const bf16x8*)(Qrow + q * 8);
    bf16x8 aq1 = *(const bf16x8*)(Qrow + 32 + q * 8);

    // staging geometry: wave w issue i covers LDS bytes [(w*2+i)*1024, +1024)
    // lane l -> row (w*2+i)*8 + (l>>3), col16 l&7; source col pre-swizzled.
    int srow = lane >> 3;                        // 0..7  == (row & 7)
    int swz  = ((lane & 7) ^ srow) << 3;         // swizzled source col (elems)
    int r0 = (w * 2 + 0) * 8 + srow;
    int r1 = (w * 2 + 1) * 8 + srow;
    const __bf16* Kg0 = Kg + (size_t)r0 * 64 + swz;
    const __bf16* Kg1 = Kg + (size_t)r1 * 64 + swz;
    const __bf16* Vg0 = Vg + (size_t)r0 * TT + swz;
    const __bf16* Vg1 = Vg + (size_t)r1 * TT + swz;
    __bf16* Kd0 = Ksh + (w * 2 + 0) * 512;
    __bf16* Kd1 = Ksh + (w * 2 + 1) * 512;

    f32x4 o_acc[4] = {};
    float den_lane = 0.f;          // partial softmax denom for q-row w*16+ln
    int qrow_l = w * 16 + ln;

    int cur = 0;
    gl_lds16(Kg0 + st0 * 4096, Kd0);
    gl_lds16(Kg1 + st0 * 4096, Kd1);
    gl_lds16(Vg0 + st0 * 64, Vsh[0] + (w * 2 + 0) * 512);
    gl_lds16(Vg1 + st0 * 64, Vsh[0] + (w * 2 + 1) * 512);

    int kswz = ln & 7;   // row&7 for all swizzled reads below (rows stride 16)
    for (int st = st0; st < st1; st++) {
        __syncthreads();   // staged K/V landed (vmcnt drain); prior P/V readers done

        // S^T = K Q^T: wave w computes S^T[all 64 s][its 16 q-cols]
        f32x4 st_acc[4] = {};
        #pragma unroll
        for (int mt = 0; mt < 4; mt++) {
            int r = mt * 16 + ln;
            bf16x8 k0v = *(const bf16x8*)&Ksh[r * 64 + ((q ^ kswz) << 3)];
            st_acc[mt] = __builtin_amdgcn_mfma_f32_16x16x32_bf16(k0v, aq0, st_acc[mt], 0, 0, 0);
            bf16x8 k1v = *(const bf16x8*)&Ksh[r * 64 + (((q + 4) ^ kswz) << 3)];
            st_acc[mt] = __builtin_amdgcn_mfma_f32_16x16x32_bf16(k1v, aq1, st_acc[mt], 0, 0, 0);
        }

        // P = exp(S/8), causal mask on diagonal tile. Lane holds 4 consecutive s
        // (mt*16 + q*4 + r) for its q-row -> one bf16x4 store per mt.
        bool diag = (st == qt);
        #pragma unroll
        for (int mt = 0; mt < 4; mt++) {
            int s0i = mt * 16 + q * 4;
            bf16x4 p4;
            #pragma unroll
            for (int r = 0; r < 4; r++) {
                float p;
                if (diag && (s0i + r) > qrow_l) p = 0.f;
                else p = exp2f(st_acc[mt][r] * 0.18033688011112042f);  // /8 * log2(e)
                den_lane += p;
                p4[r] = (__bf16)p;
            }
            *(bf16x4*)&Ps[qrow_l * PPAD + s0i] = p4;
        }
        __syncthreads();   // P visible; all waves done reading K

        if (st + 1 < st1) {   // prefetch next tile under PV (K dead, V alt buffer)
            gl_lds16(Kg0 + (st + 1) * 4096, Kd0);
            gl_lds16(Kg1 + (st + 1) * 4096, Kd1);
            gl_lds16(Vg0 + (st + 1) * 64, Vsh[cur ^ 1] + (w * 2 + 0) * 512);
            gl_lds16(Vg1 + (st + 1) * 64, Vsh[cur ^ 1] + (w * 2 + 1) * 512);
        }

        // O^T += V^T P^T : wave w owns d-rows w*16..+16, all 64 q-cols
        #pragma unroll
        for (int ks = 0; ks < 2; ks++) {
            bf16x8 af = *(const bf16x8*)&Vsh[cur][(w * 16 + ln) * 64 + (((ks * 4 + q) ^ kswz) << 3)];
            #pragma unroll
            for (int nt = 0; nt < 4; nt++) {
                bf16x8 bfr = *(const bf16x8*)&Ps[(nt * 16 + ln) * PPAD + ks * 32 + q * 8];
                o_acc[nt] = __builtin_amdgcn_mfma_f32_16x16x32_bf16(af, bfr, o_acc[nt], 0, 0, 0);
            }
        }
        cur ^= 1;
    }

    // den: lanes {ln, ln+16, ln+32, ln+48} hold s-partitions of q-row w*16+ln
    den_lane += __shfl_xor(den_lane, 16, 64);
    den_lane += __shfl_xor(den_lane, 32, 64);
    size_t slot = (size_t)nh * NCHUNK + u;
    if (lane < 16)
        pden[slot * 64 + qrow_l] = den_lane;

    #pragma unroll
    for (int nt = 0; nt < 4; nt++)
        *(f32x4*)&po[(slot << 12) + (size_t)(nt * 16 + ln) * 64 + w * 16 + q * 4] = o_acc[nt];
}

// ---------------- fused split-KV combine + residual + LayerNorm ----------------
__global__ __launch_bounds__(256) void add_ln_attn_kernel(float* __restrict__ h,
    __bf16* __restrict__ hb, const float* __restrict__ po, const float* __restrict__ pden,
    const float* __restrict__ g, const float* __restrict__ b)
{
    int w = threadIdx.x >> 6, lane = threadIdx.x & 63;
    int row = (blockIdx.x << 2) + w;          // n*1024 + t
    int n = row >> 10, t = row & (TT - 1);
    int qt = t >> 6, qrow = t & 63;
    int hh = lane >> 3;
    int d0 = (lane & 7) * 8;
    size_t base_nh = (size_t)(n * NHD + hh) * NCHUNK;

    size_t sa = base_nh + C_UA[qt];
    const float* pa = po + (sa << 12) + (size_t)qrow * 64 + d0;
    f32x4 a0 = *(const f32x4*)pa;
    f32x4 a1 = *(const f32x4*)(pa + 4);
    float den = pden[sa * 64 + qrow];
    if (qt >= 8) {
        size_t sb = base_nh + C_UB[qt];
        const float* pb2 = po + (sb << 12) + (size_t)qrow * 64 + d0;
        a0 += *(const f32x4*)pb2;
        a1 += *(const f32x4*)(pb2 + 4);
        den += pden[sb * 64 + qrow];
    }
    float inv = 1.0f / den;

    size_t base = (size_t)row * DM + lane * 8;
    f32x4 x0 = *(const f32x4*)&h[base];
    f32x4 x1 = *(const f32x4*)&h[base + 4];
    x0 += a0 * inv;
    x1 += a1 * inv;

    float s1 = x0[0]+x0[1]+x0[2]+x0[3] + x1[0]+x1[1]+x1[2]+x1[3];
    float s2 = x0[0]*x0[0]+x0[1]*x0[1]+x0[2]*x0[2]+x0[3]*x0[3]
             + x1[0]*x1[0]+x1[1]*x1[1]+x1[2]*x1[2]+x1[3]*x1[3];
    #pragma unroll
    for (int m = 1; m < 64; m <<= 1) {
        s1 += __shfl_xor(s1, m, 64);
        s2 += __shfl_xor(s2, m, 64);
    }
    float mean = s1 * (1.0f / 512.0f);
    float var = s2 * (1.0f / 512.0f) - mean * mean;
    float rstd = rsqrtf(var + 1e-3f);

    f32x4 gg0 = *(const f32x4*)&g[lane * 8];
    f32x4 gg1 = *(const f32x4*)&g[lane * 8 + 4];
    f32x4 bb0 = *(const f32x4*)&b[lane * 8];
    f32x4 bb1 = *(const f32x4*)&b[lane * 8 + 4];
    f32x4 o0, o1;
    bf16x8 pb;
    #pragma unroll
    for (int i = 0; i < 4; i++) {
        o0[i] = gg0[i] * ((x0[i] - mean) * rstd) + bb0[i];
        o1[i] = gg1[i] * ((x1[i] - mean) * rstd) + bb1[i];
        pb[i] = (__bf16)o0[i];
        pb[4 + i] = (__bf16)o1[i];
    }
    *(f32x4*)&h[base] = o0;
    *(f32x4*)&h[base + 4] = o1;
    *(bf16x8*)(hb + base) = pb;
}

// ---------------- residual add + LayerNorm (one wave per row) ----------------
__global__ __launch_bounds__(256) void add_ln_kernel(float* __restrict__ h,
    __bf16* __restrict__ hb, const float* __restrict__ a,
    const float* __restrict__ g, const float* __restrict__ b)
{
    int w = threadIdx.x >> 6, lane = threadIdx.x & 63;
    int row = (blockIdx.x << 2) + w;
    size_t base4 = (size_t)row * (DM / 4);
    const float4* h4 = (const float4*)h;
    const float4* a4 = (const float4*)a;
    float4 x0 = h4[base4 + lane];
    float4 x1 = h4[base4 + 64 + lane];
    float4 y0 = a4[base4 + lane];
    float4 y1 = a4[base4 + 64 + lane];
    x0.x += y0.x; x0.y += y0.y; x0.z += y0.z; x0.w += y0.w;
    x1.x += y1.x; x1.y += y1.y; x1.z += y1.z; x1.w += y1.w;
    float s1 = x0.x + x0.y + x0.z + x0.w + x1.x + x1.y + x1.z + x1.w;
    float s2 = x0.x*x0.x + x0.y*x0.y + x0.z*x0.z + x0.w*x0.w
             + x1.x*x1.x + x1.y*x1.y + x1.z*x1.z + x1.w*x1.w;
    #pragma unroll
    for (int m = 1; m < 64; m <<= 1) {
        s1 += __shfl_xor(s1, m, 64);
        s2 += __shfl_xor(s2, m, 64);
    }
    float mean = s1 * (1.0f / 512.0f);
    float var = s2 * (1.0f / 512.0f) - mean * mean;
    float rstd = rsqrtf(var + 1e-3f);
    const float4* g4 = (const float4*)g;
    const float4* b4 = (const float4*)b;
    float4 gg0 = g4[lane], gg1 = g4[64 + lane];
    float4 bb0 = b4[lane], bb1 = b4[64 + lane];
    float4 o0, o1;
    o0.x = gg0.x * ((x0.x - mean) * rstd) + bb0.x;
    o0.y = gg0.y * ((x0.y - mean) * rstd) + bb0.y;
    o0.z = gg0.z * ((x0.z - mean) * rstd) + bb0.z;
    o0.w = gg0.w * ((x0.w - mean) * rstd) + bb0.w;
    o1.x = gg1.x * ((x1.x - mean) * rstd) + bb1.x;
    o1.y = gg1.y * ((x1.y - mean) * rstd) + bb1.y;
    o1.z = gg1.z * ((x1.z - mean) * rstd) + bb1.z;
    o1.w = gg1.w * ((x1.w - mean) * rstd) + bb1.w;
    ((float4*)h)[base4 + lane] = o0;
    ((float4*)h)[base4 + 64 + lane] = o1;
    bf16x4 p0, p1;
    p0[0] = (__bf16)o0.x; p0[1] = (__bf16)o0.y; p0[2] = (__bf16)o0.z; p0[3] = (__bf16)o0.w;
    p1[0] = (__bf16)o1.x; p1[1] = (__bf16)o1.y; p1[2] = (__bf16)o1.z; p1[3] = (__bf16)o1.w;
    *(bf16x4*)(hb + (size_t)row * DM + lane * 4) = p0;
    *(bf16x4*)(hb + (size_t)row * DM + 256 + lane * 4) = p1;
}

extern "C" void kernel_launch(void* const* d_in, const int* in_sizes, int n_in,
                              void* d_out, int out_size, void* d_ws, size_t ws_size,
                              hipStream_t stream) {
    const int*   x     = (const int*)d_in[0];
    const float* emb   = (const float*)d_in[1];
    const float* Wqkv  = (const float*)d_in[2];
    const float* bqkv  = (const float*)d_in[3];
    const float* Wff   = (const float*)d_in[4];
    const float* bff   = (const float*)d_in[5];
    const float* Wo    = (const float*)d_in[6];
    const float* bo    = (const float*)d_in[7];
    const float* g1    = (const float*)d_in[8];
    const float* beta1 = (const float*)d_in[9];
    const float* g2    = (const float*)d_in[10];
    const float* beta2 = (const float*)d_in[11];

    float* h = (float*)d_out;               // [4096, 512] running hidden state
    char* w = (char*)d_ws;
    __bf16* qkvb = (__bf16*)w;                        // 12,582,912 B (Q|K|V^T bf16)
    __bf16* ffb  = (__bf16*)w;                        // aliases qkv (dead after attn)
    float*  abuf = (float*)(w + 25165824);            //  8,388,608 B (FF2 out)
    __bf16* hb   = (__bf16*)(w + 33554432);           //  4,194,304 B
    __bf16* WtQ  = (__bf16*)(w + 37748736);           //  9,437,184 B  [L][1536][512] (perm'd rows)
    __bf16* WtF  = (__bf16*)(w + 47185920);           //  6,291,456 B  [L][1024][512]
    __bf16* WtO  = (__bf16*)(w + 53477376);           //  6,291,456 B  [L][512][1024]
    float*  po   = (float*)(w + 59768832);            // 12,582,912 B  [32*24][64][64]
    float*  pden = (float*)(w + 80740352);            //    196,608 B  [32*24][64]
    float*  bqkv_p = (float*)(w + 81068032);          //     36,864 B  [L][1536] perm'd bias

    convert_all_kernel<<<dim3(1792, 1, LAYERS), 256, 0, stream>>>(
        Wqkv, Wff, Wo, bqkv, WtQ, WtF, WtO, bqkv_p);

    embed_pos_kernel<<<MROWS, 256, 0, stream>>>(x, emb, h, hb);

    for (int l = 0; l < LAYERS; l++) {
        const float* bff_l  = bff  + (size_t)l * DFFD;
        const float* bo_l   = bo   + (size_t)l * DM;

        // QKV projection: 128x64 tiles -> 768 blocks (3/CU)
        gemm2p<128, 64, 2><<<dim3(24, 32), 256, 0, stream>>>(
            hb, WtQ + (size_t)l * 1536 * 512, bqkv_p + l * 1536, qkvb, MROWS, 3 * DM, 512);

        attn_partial_kernel<<<dim3(NCHUNK, NB * NHD), 256, 0, stream>>>(
            qkvb, qkvb + PERBUF, qkvb + 2 * (size_t)PERBUF, po, pden);

        // fused: combine split-KV partials + residual + LN1
        add_ln_attn_kernel<<<MROWS / 4, 256, 0, stream>>>(
            h, hb, po, pden, g1 + l * DM, beta1 + l * DM);

        // FF1: relu(h @ Wff + bff) -> bf16; 128x64 tiles -> 512 blocks (2/CU)
        gemm2p<128, 64, 1><<<dim3(16, 32), 256, 0, stream>>>(
            hb, WtF + (size_t)l * 1024 * 512, bff_l, ffb, MROWS, DFFD, 512);

        // FF2: ff @ Wo + bo -> fp32; 64x64 tiles -> 512 blocks (2/CU)
        gemm2p<64, 64, 0><<<dim3(8, 64), 256, 0, stream>>>(
            ffb, WtO + (size_t)l * 512 * 1024, bo_l, abuf, MROWS, DM, 1024);

        add_ln_kernel<<<MROWS / 4, 256, 0, stream>>>(h, hb, abuf, g2 + l * DM, beta2 + l * DM);
    }
}

// Round 7
// 629.087 us; speedup vs baseline: 1.3159x; 1.0037x over previous
//
#include <hip/hip_runtime.h>
#include <hip/hip_bf16.h>
#include <math.h>

#define DM   512
#define TT   1024
#define NB   4
#define NHD  8
#define LAYERS 6
#define DFFD 1024
#define MROWS (NB*TT)          // 4096
#define PERBUF (NB*NHD*TT*64)  // 2097152 elems per Q/K/V buffer

typedef __bf16 bf16x8 __attribute__((ext_vector_type(8)));
typedef __bf16 bf16x4 __attribute__((ext_vector_type(4)));
typedef float f32x4 __attribute__((ext_vector_type(4)));

// async global->LDS, 16B per lane; LDS base must be wave-uniform (m104/m108)
__device__ __forceinline__ void gl_lds16(const __bf16* g, __bf16* l) {
    __builtin_amdgcn_global_load_lds((const __attribute__((address_space(1))) void*)g,
                                     (__attribute__((address_space(3))) void*)l, 16, 0, 0);
}

// split-KV chunk tables (NCHUNK=24): qt 0-7 one chunk, qt 8-15 two chunks.
// Ordered heavy-first (u=0 dispatched first carries longest chains).
__constant__ signed char C_QT[24]  = {15,15,14, 7,14,13,13,12, 6,12,11,11,10, 5,10, 9, 9, 8, 4, 8, 3, 2, 1, 0};
__constant__ signed char C_ST0[24] = { 0, 8, 0, 0, 8, 0, 7, 0, 0, 7, 0, 6, 0, 0, 6, 0, 5, 0, 0, 5, 0, 0, 0, 0};
__constant__ signed char C_ST1[24] = { 8,16, 8, 8,15, 7,14, 7, 7,13, 6,12, 6, 6,11, 5,10, 5, 5, 9, 4, 3, 2, 1};
// combine: qt -> chunk ids (second valid only for qt>=8)
__constant__ unsigned char C_UA[16] = {23,22,21,20,18,13,8,3,17,15,12,10,7,5,2,0};
__constant__ unsigned char C_UB[16] = { 0, 0, 0, 0, 0, 0,0,0,19,16,14,11,9,6,4,1};
#define NCHUNK 24

// ---------------- embedding + positional encoding (fp32 h + bf16 shadow) ----------------
__global__ __launch_bounds__(256) void embed_pos_kernel(const int* __restrict__ x,
    const float* __restrict__ emb, float* __restrict__ h, __bf16* __restrict__ hb)
{
    int row = blockIdx.x;            // n*T + t
    int t = row & (TT - 1);
    int tok = x[row];
    const float* e = emb + (size_t)tok * DM;
    float* out = h + (size_t)row * DM;
    __bf16* outb = hb + (size_t)row * DM;
    for (int i = threadIdx.x; i < DM; i += 256) {
        float val = e[i] * 22.62741699796952f;   // sqrt(512)
        int pair = i >> 1;
        float rate = powf(10000.0f, -(float)pair * (1.0f / 256.0f));
        float ang = (float)t * rate;
        float pe = (i & 1) ? cosf(ang) : sinf(ang);
        float v = val + pe;
        out[i] = v;
        outb[i] = (__bf16)v;
    }
}

// ---------------- all-weight convert + transpose (one dispatch) ----------------
// W[K,N] fp32 -> Wt[N,K] bf16. For Wqkv, output columns are PERMUTED:
// original col c -> row (c%3)*512 + c/3, grouping Q|K|V with inner [h][d].
__global__ __launch_bounds__(256) void convert_all_kernel(
    const float* __restrict__ Wqkv, const float* __restrict__ Wff, const float* __restrict__ Wo,
    const float* __restrict__ bqkv,
    __bf16* __restrict__ WtQ, __bf16* __restrict__ WtF, __bf16* __restrict__ WtO,
    float* __restrict__ bqkv_p)
{
    __shared__ float tile[32][33];
    int l = blockIdx.z;
    int t = blockIdx.x;
    const float* W; __bf16* Wt; int K, N, bx, by; bool perm = false;
    if (t < 768)       { W = Wqkv; Wt = WtQ; K = 512;  N = 1536; bx = t & 15;  by = t >> 4; perm = true; }
    else if (t < 1280) { int u = t - 768;  W = Wff; Wt = WtF; K = 512;  N = 1024; bx = u & 15; by = u >> 4; }
    else               { int u = t - 1280; W = Wo;  Wt = WtO; K = 1024; N = 512;  bx = u & 31; by = u >> 5; }
    int k0 = bx * 32, n0 = by * 32;
    const float* Wl = W + (size_t)l * K * N;
    __bf16* Wtl = Wt + (size_t)l * K * N;
    int tx = threadIdx.x & 31, ty = threadIdx.x >> 5;   // ty 0..7
    #pragma unroll
    for (int i = ty; i < 32; i += 8)
        tile[i][tx] = Wl[(size_t)(k0 + i) * N + n0 + tx];
    if (perm && bx == 0 && ty == 0) {                   // permute bias once per col-chunk
        int c = n0 + tx;
        bqkv_p[l * 1536 + (c % 3) * 512 + c / 3] = bqkv[(size_t)l * 1536 + c];
    }
    __syncthreads();
    #pragma unroll
    for (int i = ty; i < 32; i += 8) {
        int c = n0 + i;
        int row = perm ? ((c % 3) * 512 + c / 3) : c;
        Wtl[(size_t)row * K + k0 + tx] = (__bf16)tile[tx][i];
    }
}

// ---------------- bf16 MFMA GEMM, templated tile, 2-phase pipelined 32-K panels ----------------
// LDS BANK-CONFLICT FIX (this round): row-major [rows][32] bf16 tiles have 64B rows ->
// bank stride 16, so unswizzled fragment reads are 8-WAY conflicted (bank =
// (ln&1)*16 + q*4). Swizzle the 16B slot with row bits 1-2: slot = q ^ ((row>>1)&3)
// -> bank = (ln&1)*16 + (q^((ln>>1)&3))*4 = exactly 2 lanes/bank (free, m136).
// Both-sides-or-neither (rule #21): gl_lds dest stays linear; the global SOURCE col
// is pre-swizzled in staging, and reads apply the same involution (kx).
// MODE 0: fp32 C out (+bias). MODE 1: relu -> bf16. MODE 2: QKV scatter, PERMUTED cols.
template<int BM, int BN, int MODE>
__global__ __launch_bounds__(256) void gemm2p(const __bf16* __restrict__ A,
    const __bf16* __restrict__ Bt, const float* __restrict__ bias,
    void* __restrict__ Cv, int M, int Nc, int K)
{
    constexpr int WM = BM / 2, WN = BN / 2;
    constexpr int MT = WM / 16, NT = WN / 16;
    constexpr int ACH = BM / 64;   // 16-row A chunks staged per wave
    constexpr int BCH = BN / 64;   // 16-row B chunks staged per wave
    __shared__ __align__(16) __bf16 As[2][BM * 32];
    __shared__ __align__(16) __bf16 Bs[2][BN * 32];
    int tid = threadIdx.x;
    int lane = tid & 63;
    int wave = tid >> 6;
    int ln = lane & 15, q = lane >> 4;
    int wrow = (wave >> 1) * WM, wcol = (wave & 1) * WN;
    int n0 = blockIdx.x * BN, m0 = blockIdx.y * BM;

    f32x4 acc[MT][NT] = {};

    const __bf16* Ab = A + (size_t)m0 * K;
    const __bf16* Bb = Bt + (size_t)n0 * K;
    int srow = lane >> 2;                                  // 0..15
    int scol = ((lane & 3) ^ ((lane >> 3) & 3)) * 8;       // pre-swizzled source slot
    int kx   = (q ^ ((ln >> 1) & 3)) * 8;                  // read-side swizzled slot

    const __bf16* Aga[ACH];
    const __bf16* Bga[BCH];
    #pragma unroll
    for (int i = 0; i < ACH; i++)
        Aga[i] = Ab + (size_t)(wave * (16 * ACH) + 16 * i + srow) * K + scol;
    #pragma unroll
    for (int i = 0; i < BCH; i++)
        Bga[i] = Bb + (size_t)(wave * (16 * BCH) + 16 * i + srow) * K + scol;

    auto STAGE = [&](int kp, int buf) {
        #pragma unroll
        for (int i = 0; i < ACH; i++)
            gl_lds16(Aga[i] + kp, As[buf] + (wave * (16 * ACH) + 16 * i) * 32);
        #pragma unroll
        for (int i = 0; i < BCH; i++)
            gl_lds16(Bga[i] + kp, Bs[buf] + (wave * (16 * BCH) + 16 * i) * 32);
    };
    auto COMPUTE = [&](int buf) {
        bf16x8 af[MT], bfr[NT];
        #pragma unroll
        for (int mt = 0; mt < MT; mt++)
            af[mt] = *(const bf16x8*)&As[buf][(wrow + mt * 16 + ln) * 32 + kx];
        #pragma unroll
        for (int nt = 0; nt < NT; nt++)
            bfr[nt] = *(const bf16x8*)&Bs[buf][(wcol + nt * 16 + ln) * 32 + kx];
        #pragma unroll
        for (int mt = 0; mt < MT; mt++)
            #pragma unroll
            for (int nt = 0; nt < NT; nt++)
                acc[mt][nt] = __builtin_amdgcn_mfma_f32_16x16x32_bf16(af[mt], bfr[nt], acc[mt][nt], 0, 0, 0);
    };

    STAGE(0, 0);
    __syncthreads();
    int kp = 0;
    for (; kp + 64 < K; kp += 64) {
        STAGE(kp + 32, 1);
        COMPUTE(0);
        __syncthreads();      // drain: panel kp+32 landed; buf0 readers done
        STAGE(kp + 64, 0);
        COMPUTE(1);
        __syncthreads();      // drain: panel kp+64 landed; buf1 readers done
    }
    STAGE(kp + 32, 1);
    COMPUTE(0);
    __syncthreads();
    COMPUTE(1);

    #pragma unroll
    for (int mt = 0; mt < MT; mt++) {
        int mbase = m0 + wrow + mt * 16 + q * 4;
        if constexpr (MODE == 0) {
            float* C = (float*)Cv;
            #pragma unroll
            for (int r = 0; r < 4; r++) {
                int m = mbase + r;
                #pragma unroll
                for (int nt = 0; nt < NT; nt++) {
                    int c = n0 + wcol + nt * 16 + ln;
                    C[(size_t)m * Nc + c] = acc[mt][nt][r] + bias[c];
                }
            }
        } else if constexpr (MODE == 1) {
            __bf16* Cb = (__bf16*)Cv;
            #pragma unroll
            for (int r = 0; r < 4; r++) {
                int m = mbase + r;
                #pragma unroll
                for (int nt = 0; nt < NT; nt++) {
                    int c = n0 + wcol + nt * 16 + ln;
                    float val = acc[mt][nt][r] + bias[c];
                    Cb[(size_t)m * Nc + c] = (__bf16)fmaxf(val, 0.f);
                }
            }
        } else {
            __bf16* Cb = (__bf16*)Cv;
            int n = mbase >> 10, t = mbase & (TT - 1);
            #pragma unroll
            for (int nt = 0; nt < NT; nt++) {
                int c = n0 + wcol + nt * 16 + ln;
                int buf = c >> 9;            // uniform within the 16-col group
                int hd = c & 511;
                int hh = hd >> 6, d = hd & 63;
                float bv = bias[c];
                if (buf == 2) {              // V^T [n,h,d,t]: 4 consecutive t -> one 8B store
                    size_t idx = 2 * (size_t)PERBUF + (((size_t)(n * NHD + hh) * 64 + d) << 10) + t;
                    bf16x4 v4;
                    #pragma unroll
                    for (int r = 0; r < 4; r++) v4[r] = (__bf16)(acc[mt][nt][r] + bv);
                    *(bf16x4*)&Cb[idx] = v4;
                } else {                     // Q,K [n,h,t,d]
                    size_t base = (size_t)buf * PERBUF + (((size_t)(n * NHD + hh) * TT + t) << 6) + d;
                    #pragma unroll
                    for (int r = 0; r < 4; r++)
                        Cb[base + (size_t)(r << 6)] = (__bf16)(acc[mt][nt][r] + bv);
                }
            }
        }
    }
}

// ---------------- split-KV MFMA flash attention (NCHUNK=24, table-driven) ----------------
// Q fragments in registers. K single-buffered + V double-buffered in LDS via
// async global_load_lds with XOR-swizzled source (linear dest, swizzled read).
// QK^T computed SWAPPED (S^T = K Q^T): lane holds 4 consecutive s per q-row ->
// P store is 4x bf16x4, den reduction 2 shuffles. 768 blocks (3/CU), chains <= 8.
#define PPAD 72
__global__ __launch_bounds__(256) void attn_partial_kernel(const __bf16* __restrict__ qb,
    const __bf16* __restrict__ kb, const __bf16* __restrict__ vtb,
    float* __restrict__ po, float* __restrict__ pden)
{
    __shared__ __align__(16) __bf16 Ksh[64 * 64];      // K tile [s][d], swizzled
    __shared__ __align__(16) __bf16 Vsh[2][64 * 64];   // V^T tile [d][s], swizzled
    __shared__ __align__(16) __bf16 Ps[64 * PPAD];     // P tile [q][s], padded

    int u = blockIdx.x;                  // heavy chunks at low u (dispatch first)
    int nh = blockIdx.y;
    int qt  = C_QT[u];
    int st0 = C_ST0[u];
    int st1 = C_ST1[u];

    int tid = threadIdx.x;
    int lane = tid & 63, w = tid >> 6;
    int ln = lane & 15, q = lane >> 4;

    const __bf16* Kg = kb + (size_t)nh * TT * 64;
    const __bf16* Vg = vtb + (size_t)nh * 64 * TT;   // [d][t]

    // Q fragments in registers: wave w owns q-rows w*16..+16 of this q-tile
    const __bf16* Qrow = qb + ((size_t)nh * TT + (size_t)qt * 64 + w * 16 + ln) * 64;
    bf16x8 aq0 = *(const bf16x8*)(Qrow + q * 8);
    bf16x8 aq1 = *(const bf16x8*)(Qrow + 32 + q * 8);

    // staging geometry: wave w issue i covers LDS bytes [(w*2+i)*1024, +1024)
    // lane l -> row (w*2+i)*8 + (l>>3), col16 l&7; source col pre-swizzled.
    int srow = lane >> 3;                        // 0..7  == (row & 7)
    int swz  = ((lane & 7) ^ srow) << 3;         // swizzled source col (elems)
    int r0 = (w * 2 + 0) * 8 + srow;
    int r1 = (w * 2 + 1) * 8 + srow;
    const __bf16* Kg0 = Kg + (size_t)r0 * 64 + swz;
    const __bf16* Kg1 = Kg + (size_t)r1 * 64 + swz;
    const __bf16* Vg0 = Vg + (size_t)r0 * TT + swz;
    const __bf16* Vg1 = Vg + (size_t)r1 * TT + swz;
    __bf16* Kd0 = Ksh + (w * 2 + 0) * 512;
    __bf16* Kd1 = Ksh + (w * 2 + 1) * 512;

    f32x4 o_acc[4] = {};
    float den_lane = 0.f;          // partial softmax denom for q-row w*16+ln
    int qrow_l = w * 16 + ln;

    int cur = 0;
    gl_lds16(Kg0 + st0 * 4096, Kd0);
    gl_lds16(Kg1 + st0 * 4096, Kd1);
    gl_lds16(Vg0 + st0 * 64, Vsh[0] + (w * 2 + 0) * 512);
    gl_lds16(Vg1 + st0 * 64, Vsh[0] + (w * 2 + 1) * 512);

    int kswz = ln & 7;   // row&7 for all swizzled reads below (rows stride 16)
    for (int st = st0; st < st1; st++) {
        __syncthreads();   // staged K/V landed (vmcnt drain); prior P/V readers done

        // S^T = K Q^T: wave w computes S^T[all 64 s][its 16 q-cols]
        f32x4 st_acc[4] = {};
        #pragma unroll
        for (int mt = 0; mt < 4; mt++) {
            int r = mt * 16 + ln;
            bf16x8 k0v = *(const bf16x8*)&Ksh[r * 64 + ((q ^ kswz) << 3)];
            st_acc[mt] = __builtin_amdgcn_mfma_f32_16x16x32_bf16(k0v, aq0, st_acc[mt], 0, 0, 0);
            bf16x8 k1v = *(const bf16x8*)&Ksh[r * 64 + (((q + 4) ^ kswz) << 3)];
            st_acc[mt] = __builtin_amdgcn_mfma_f32_16x16x32_bf16(k1v, aq1, st_acc[mt], 0, 0, 0);
        }

        // P = exp(S/8), causal mask on diagonal tile. Lane holds 4 consecutive s
        // (mt*16 + q*4 + r) for its q-row -> one bf16x4 store per mt.
        bool diag = (st == qt);
        #pragma unroll
        for (int mt = 0; mt < 4; mt++) {
            int s0i = mt * 16 + q * 4;
            bf16x4 p4;
            #pragma unroll
            for (int r = 0; r < 4; r++) {
                float p;
                if (diag && (s0i + r) > qrow_l) p = 0.f;
                else p = exp2f(st_acc[mt][r] * 0.18033688011112042f);  // /8 * log2(e)
                den_lane += p;
                p4[r] = (__bf16)p;
            }
            *(bf16x4*)&Ps[qrow_l * PPAD + s0i] = p4;
        }
        __syncthreads();   // P visible; all waves done reading K

        if (st + 1 < st1) {   // prefetch next tile under PV (K dead, V alt buffer)
            gl_lds16(Kg0 + (st + 1) * 4096, Kd0);
            gl_lds16(Kg1 + (st + 1) * 4096, Kd1);
            gl_lds16(Vg0 + (st + 1) * 64, Vsh[cur ^ 1] + (w * 2 + 0) * 512);
            gl_lds16(Vg1 + (st + 1) * 64, Vsh[cur ^ 1] + (w * 2 + 1) * 512);
        }

        // O^T += V^T P^T : wave w owns d-rows w*16..+16, all 64 q-cols
        #pragma unroll
        for (int ks = 0; ks < 2; ks++) {
            bf16x8 af = *(const bf16x8*)&Vsh[cur][(w * 16 + ln) * 64 + (((ks * 4 + q) ^ kswz) << 3)];
            #pragma unroll
            for (int nt = 0; nt < 4; nt++) {
                bf16x8 bfr = *(const bf16x8*)&Ps[(nt * 16 + ln) * PPAD + ks * 32 + q * 8];
                o_acc[nt] = __builtin_amdgcn_mfma_f32_16x16x32_bf16(af, bfr, o_acc[nt], 0, 0, 0);
            }
        }
        cur ^= 1;
    }

    // den: lanes {ln, ln+16, ln+32, ln+48} hold s-partitions of q-row w*16+ln
    den_lane += __shfl_xor(den_lane, 16, 64);
    den_lane += __shfl_xor(den_lane, 32, 64);
    size_t slot = (size_t)nh * NCHUNK + u;
    if (lane < 16)
        pden[slot * 64 + qrow_l] = den_lane;

    #pragma unroll
    for (int nt = 0; nt < 4; nt++)
        *(f32x4*)&po[(slot << 12) + (size_t)(nt * 16 + ln) * 64 + w * 16 + q * 4] = o_acc[nt];
}

// ---------------- fused split-KV combine + residual + LayerNorm ----------------
__global__ __launch_bounds__(256) void add_ln_attn_kernel(float* __restrict__ h,
    __bf16* __restrict__ hb, const float* __restrict__ po, const float* __restrict__ pden,
    const float* __restrict__ g, const float* __restrict__ b)
{
    int w = threadIdx.x >> 6, lane = threadIdx.x & 63;
    int row = (blockIdx.x << 2) + w;          // n*1024 + t
    int n = row >> 10, t = row & (TT - 1);
    int qt = t >> 6, qrow = t & 63;
    int hh = lane >> 3;
    int d0 = (lane & 7) * 8;
    size_t base_nh = (size_t)(n * NHD + hh) * NCHUNK;

    size_t sa = base_nh + C_UA[qt];
    const float* pa = po + (sa << 12) + (size_t)qrow * 64 + d0;
    f32x4 a0 = *(const f32x4*)pa;
    f32x4 a1 = *(const f32x4*)(pa + 4);
    float den = pden[sa * 64 + qrow];
    if (qt >= 8) {
        size_t sb = base_nh + C_UB[qt];
        const float* pb2 = po + (sb << 12) + (size_t)qrow * 64 + d0;
        a0 += *(const f32x4*)pb2;
        a1 += *(const f32x4*)(pb2 + 4);
        den += pden[sb * 64 + qrow];
    }
    float inv = 1.0f / den;

    size_t base = (size_t)row * DM + lane * 8;
    f32x4 x0 = *(const f32x4*)&h[base];
    f32x4 x1 = *(const f32x4*)&h[base + 4];
    x0 += a0 * inv;
    x1 += a1 * inv;

    float s1 = x0[0]+x0[1]+x0[2]+x0[3] + x1[0]+x1[1]+x1[2]+x1[3];
    float s2 = x0[0]*x0[0]+x0[1]*x0[1]+x0[2]*x0[2]+x0[3]*x0[3]
             + x1[0]*x1[0]+x1[1]*x1[1]+x1[2]*x1[2]+x1[3]*x1[3];
    #pragma unroll
    for (int m = 1; m < 64; m <<= 1) {
        s1 += __shfl_xor(s1, m, 64);
        s2 += __shfl_xor(s2, m, 64);
    }
    float mean = s1 * (1.0f / 512.0f);
    float var = s2 * (1.0f / 512.0f) - mean * mean;
    float rstd = rsqrtf(var + 1e-3f);

    f32x4 gg0 = *(const f32x4*)&g[lane * 8];
    f32x4 gg1 = *(const f32x4*)&g[lane * 8 + 4];
    f32x4 bb0 = *(const f32x4*)&b[lane * 8];
    f32x4 bb1 = *(const f32x4*)&b[lane * 8 + 4];
    f32x4 o0, o1;
    bf16x8 pb;
    #pragma unroll
    for (int i = 0; i < 4; i++) {
        o0[i] = gg0[i] * ((x0[i] - mean) * rstd) + bb0[i];
        o1[i] = gg1[i] * ((x1[i] - mean) * rstd) + bb1[i];
        pb[i] = (__bf16)o0[i];
        pb[4 + i] = (__bf16)o1[i];
    }
    *(f32x4*)&h[base] = o0;
    *(f32x4*)&h[base + 4] = o1;
    *(bf16x8*)(hb + base) = pb;
}

// ---------------- residual add + LayerNorm (one wave per row) ----------------
__global__ __launch_bounds__(256) void add_ln_kernel(float* __restrict__ h,
    __bf16* __restrict__ hb, const float* __restrict__ a,
    const float* __restrict__ g, const float* __restrict__ b)
{
    int w = threadIdx.x >> 6, lane = threadIdx.x & 63;
    int row = (blockIdx.x << 2) + w;
    size_t base4 = (size_t)row * (DM / 4);
    const float4* h4 = (const float4*)h;
    const float4* a4 = (const float4*)a;
    float4 x0 = h4[base4 + lane];
    float4 x1 = h4[base4 + 64 + lane];
    float4 y0 = a4[base4 + lane];
    float4 y1 = a4[base4 + 64 + lane];
    x0.x += y0.x; x0.y += y0.y; x0.z += y0.z; x0.w += y0.w;
    x1.x += y1.x; x1.y += y1.y; x1.z += y1.z; x1.w += y1.w;
    float s1 = x0.x + x0.y + x0.z + x0.w + x1.x + x1.y + x1.z + x1.w;
    float s2 = x0.x*x0.x + x0.y*x0.y + x0.z*x0.z + x0.w*x0.w
             + x1.x*x1.x + x1.y*x1.y + x1.z*x1.z + x1.w*x1.w;
    #pragma unroll
    for (int m = 1; m < 64; m <<= 1) {
        s1 += __shfl_xor(s1, m, 64);
        s2 += __shfl_xor(s2, m, 64);
    }
    float mean = s1 * (1.0f / 512.0f);
    float var = s2 * (1.0f / 512.0f) - mean * mean;
    float rstd = rsqrtf(var + 1e-3f);
    const float4* g4 = (const float4*)g;
    const float4* b4 = (const float4*)b;
    float4 gg0 = g4[lane], gg1 = g4[64 + lane];
    float4 bb0 = b4[lane], bb1 = b4[64 + lane];
    float4 o0, o1;
    o0.x = gg0.x * ((x0.x - mean) * rstd) + bb0.x;
    o0.y = gg0.y * ((x0.y - mean) * rstd) + bb0.y;
    o0.z = gg0.z * ((x0.z - mean) * rstd) + bb0.z;
    o0.w = gg0.w * ((x0.w - mean) * rstd) + bb0.w;
    o1.x = gg1.x * ((x1.x - mean) * rstd) + bb1.x;
    o1.y = gg1.y * ((x1.y - mean) * rstd) + bb1.y;
    o1.z = gg1.z * ((x1.z - mean) * rstd) + bb1.z;
    o1.w = gg1.w * ((x1.w - mean) * rstd) + bb1.w;
    ((float4*)h)[base4 + lane] = o0;
    ((float4*)h)[base4 + 64 + lane] = o1;
    bf16x4 p0, p1;
    p0[0] = (__bf16)o0.x; p0[1] = (__bf16)o0.y; p0[2] = (__bf16)o0.z; p0[3] = (__bf16)o0.w;
    p1[0] = (__bf16)o1.x; p1[1] = (__bf16)o1.y; p1[2] = (__bf16)o1.z; p1[3] = (__bf16)o1.w;
    *(bf16x4*)(hb + (size_t)row * DM + lane * 4) = p0;
    *(bf16x4*)(hb + (size_t)row * DM + 256 + lane * 4) = p1;
}

extern "C" void kernel_launch(void* const* d_in, const int* in_sizes, int n_in,
                              void* d_out, int out_size, void* d_ws, size_t ws_size,
                              hipStream_t stream) {
    const int*   x     = (const int*)d_in[0];
    const float* emb   = (const float*)d_in[1];
    const float* Wqkv  = (const float*)d_in[2];
    const float* bqkv  = (const float*)d_in[3];
    const float* Wff   = (const float*)d_in[4];
    const float* bff   = (const float*)d_in[5];
    const float* Wo    = (const float*)d_in[6];
    const float* bo    = (const float*)d_in[7];
    const float* g1    = (const float*)d_in[8];
    const float* beta1 = (const float*)d_in[9];
    const float* g2    = (const float*)d_in[10];
    const float* beta2 = (const float*)d_in[11];

    float* h = (float*)d_out;               // [4096, 512] running hidden state
    char* w = (char*)d_ws;
    __bf16* qkvb = (__bf16*)w;                        // 12,582,912 B (Q|K|V^T bf16)
    __bf16* ffb  = (__bf16*)w;                        // aliases qkv (dead after attn)
    float*  abuf = (float*)(w + 25165824);            //  8,388,608 B (FF2 out)
    __bf16* hb   = (__bf16*)(w + 33554432);           //  4,194,304 B
    __bf16* WtQ  = (__bf16*)(w + 37748736);           //  9,437,184 B  [L][1536][512] (perm'd rows)
    __bf16* WtF  = (__bf16*)(w + 47185920);           //  6,291,456 B  [L][1024][512]
    __bf16* WtO  = (__bf16*)(w + 53477376);           //  6,291,456 B  [L][512][1024]
    float*  po   = (float*)(w + 59768832);            // 12,582,912 B  [32*24][64][64]
    float*  pden = (float*)(w + 80740352);            //    196,608 B  [32*24][64]
    float*  bqkv_p = (float*)(w + 81068032);          //     36,864 B  [L][1536] perm'd bias

    convert_all_kernel<<<dim3(1792, 1, LAYERS), 256, 0, stream>>>(
        Wqkv, Wff, Wo, bqkv, WtQ, WtF, WtO, bqkv_p);

    embed_pos_kernel<<<MROWS, 256, 0, stream>>>(x, emb, h, hb);

    for (int l = 0; l < LAYERS; l++) {
        const float* bff_l  = bff  + (size_t)l * DFFD;
        const float* bo_l   = bo   + (size_t)l * DM;

        // QKV projection: 128x64 tiles -> 768 blocks (3/CU)
        gemm2p<128, 64, 2><<<dim3(24, 32), 256, 0, stream>>>(
            hb, WtQ + (size_t)l * 1536 * 512, bqkv_p + l * 1536, qkvb, MROWS, 3 * DM, 512);

        attn_partial_kernel<<<dim3(NCHUNK, NB * NHD), 256, 0, stream>>>(
            qkvb, qkvb + PERBUF, qkvb + 2 * (size_t)PERBUF, po, pden);

        // fused: combine split-KV partials + residual + LN1
        add_ln_attn_kernel<<<MROWS / 4, 256, 0, stream>>>(
            h, hb, po, pden, g1 + l * DM, beta1 + l * DM);

        // FF1: relu(h @ Wff + bff) -> bf16; 128x64 tiles -> 512 blocks (2/CU)
        gemm2p<128, 64, 1><<<dim3(16, 32), 256, 0, stream>>>(
            hb, WtF + (size_t)l * 1024 * 512, bff_l, ffb, MROWS, DFFD, 512);

        // FF2: ff @ Wo + bo -> fp32; 64x64 tiles -> 512 blocks (2/CU)
        gemm2p<64, 64, 0><<<dim3(8, 64), 256, 0, stream>>>(
            ffb, WtO + (size_t)l * 512 * 1024, bo_l, abuf, MROWS, DM, 1024);

        add_ln_kernel<<<MROWS / 4, 256, 0, stream>>>(h, hb, abuf, g2 + l * DM, beta2 + l * DM);
    }
}

// Round 8
// 614.725 us; speedup vs baseline: 1.3467x; 1.0234x over previous
//
#include <hip/hip_runtime.h>
#include <hip/hip_bf16.h>
#include <math.h>

#define DM   512
#define TT   1024
#define NB   4
#define NHD  8
#define LAYERS 6
#define DFFD 1024
#define MROWS (NB*TT)          // 4096
#define PERBUF (NB*NHD*TT*64)  // 2097152 elems per Q/K/V buffer

typedef __bf16 bf16x8 __attribute__((ext_vector_type(8)));
typedef __bf16 bf16x4 __attribute__((ext_vector_type(4)));
typedef float f32x4 __attribute__((ext_vector_type(4)));

// async global->LDS, 16B per lane; LDS base must be wave-uniform (m104/m108)
__device__ __forceinline__ void gl_lds16(const __bf16* g, __bf16* l) {
    __builtin_amdgcn_global_load_lds((const __attribute__((address_space(1))) void*)g,
                                     (__attribute__((address_space(3))) void*)l, 16, 0, 0);
}

// split-KV chunk tables (NCHUNK=24): qt 0-7 one chunk, qt 8-15 two chunks.
// Ordered heavy-first (u=0 dispatched first carries longest chains).
__constant__ signed char C_QT[24]  = {15,15,14, 7,14,13,13,12, 6,12,11,11,10, 5,10, 9, 9, 8, 4, 8, 3, 2, 1, 0};
__constant__ signed char C_ST0[24] = { 0, 8, 0, 0, 8, 0, 7, 0, 0, 7, 0, 6, 0, 0, 6, 0, 5, 0, 0, 5, 0, 0, 0, 0};
__constant__ signed char C_ST1[24] = { 8,16, 8, 8,15, 7,14, 7, 7,13, 6,12, 6, 6,11, 5,10, 5, 5, 9, 4, 3, 2, 1};
// combine: qt -> chunk ids (second valid only for qt>=8)
__constant__ unsigned char C_UA[16] = {23,22,21,20,18,13,8,3,17,15,12,10,7,5,2,0};
__constant__ unsigned char C_UB[16] = { 0, 0, 0, 0, 0, 0,0,0,19,16,14,11,9,6,4,1};
#define NCHUNK 24

// ---------------- embedding + positional encoding (fp32 h + bf16 shadow) ----------------
// Fast trig: powf -> exp2f (v_exp_f32), sinf/cosf -> __sinf/__cosf (native).
__global__ __launch_bounds__(256) void embed_pos_kernel(const int* __restrict__ x,
    const float* __restrict__ emb, float* __restrict__ h, __bf16* __restrict__ hb)
{
    int row = blockIdx.x;            // n*T + t
    int t = row & (TT - 1);
    int tok = x[row];
    const float* e = emb + (size_t)tok * DM;
    float* out = h + (size_t)row * DM;
    __bf16* outb = hb + (size_t)row * DM;
    for (int i = threadIdx.x; i < DM; i += 256) {
        float val = e[i] * 22.62741699796952f;   // sqrt(512)
        int pair = i >> 1;
        // 10000^(-pair/256) = exp2(-pair * log2(10000)/256)
        float rate = exp2f((float)pair * -0.051905126482615035f);
        float ang = (float)t * rate;
        float pe = (i & 1) ? __cosf(ang) : __sinf(ang);
        float v = val + pe;
        out[i] = v;
        outb[i] = (__bf16)v;
    }
}

// ---------------- all-weight convert + transpose (one dispatch) ----------------
// W[K,N] fp32 -> Wt[N,K] bf16. For Wqkv, output columns are PERMUTED:
// original col c -> row (c%3)*512 + c/3, grouping Q|K|V with inner [h][d].
__global__ __launch_bounds__(256) void convert_all_kernel(
    const float* __restrict__ Wqkv, const float* __restrict__ Wff, const float* __restrict__ Wo,
    const float* __restrict__ bqkv,
    __bf16* __restrict__ WtQ, __bf16* __restrict__ WtF, __bf16* __restrict__ WtO,
    float* __restrict__ bqkv_p)
{
    __shared__ float tile[32][33];
    int l = blockIdx.z;
    int t = blockIdx.x;
    const float* W; __bf16* Wt; int K, N, bx, by; bool perm = false;
    if (t < 768)       { W = Wqkv; Wt = WtQ; K = 512;  N = 1536; bx = t & 15;  by = t >> 4; perm = true; }
    else if (t < 1280) { int u = t - 768;  W = Wff; Wt = WtF; K = 512;  N = 1024; bx = u & 15; by = u >> 4; }
    else               { int u = t - 1280; W = Wo;  Wt = WtO; K = 1024; N = 512;  bx = u & 31; by = u >> 5; }
    int k0 = bx * 32, n0 = by * 32;
    const float* Wl = W + (size_t)l * K * N;
    __bf16* Wtl = Wt + (size_t)l * K * N;
    int tx = threadIdx.x & 31, ty = threadIdx.x >> 5;   // ty 0..7
    #pragma unroll
    for (int i = ty; i < 32; i += 8)
        tile[i][tx] = Wl[(size_t)(k0 + i) * N + n0 + tx];
    if (perm && bx == 0 && ty == 0) {                   // permute bias once per col-chunk
        int c = n0 + tx;
        bqkv_p[l * 1536 + (c % 3) * 512 + c / 3] = bqkv[(size_t)l * 1536 + c];
    }
    __syncthreads();
    #pragma unroll
    for (int i = ty; i < 32; i += 8) {
        int c = n0 + i;
        int row = perm ? ((c % 3) * 512 + c / 3) : c;
        Wtl[(size_t)row * K + k0 + tx] = (__bf16)tile[tx][i];
    }
}

// ---------------- bf16 MFMA GEMM, templated tile, 2-phase pipelined 32-K panels ----------------
// LDS reads swizzled conflict-free (R7); 2-3 blocks/CU (R5). Fragment loads via LDS (R4 lesson).
// MODE 0: bf16 C out (+bias, no relu). MODE 1: relu -> bf16. MODE 2: QKV scatter, PERMUTED cols:
// c in [0,512)=Q, [512,1024)=K (both [n,h,t,d]), [1024,1536)=V^T [n,h,d,t].
template<int BM, int BN, int MODE>
__global__ __launch_bounds__(256) void gemm2p(const __bf16* __restrict__ A,
    const __bf16* __restrict__ Bt, const float* __restrict__ bias,
    void* __restrict__ Cv, int M, int Nc, int K)
{
    constexpr int WM = BM / 2, WN = BN / 2;
    constexpr int MT = WM / 16, NT = WN / 16;
    constexpr int ACH = BM / 64;   // 16-row A chunks staged per wave
    constexpr int BCH = BN / 64;   // 16-row B chunks staged per wave
    __shared__ __align__(16) __bf16 As[2][BM * 32];
    __shared__ __align__(16) __bf16 Bs[2][BN * 32];
    int tid = threadIdx.x;
    int lane = tid & 63;
    int wave = tid >> 6;
    int ln = lane & 15, q = lane >> 4;
    int wrow = (wave >> 1) * WM, wcol = (wave & 1) * WN;
    int n0 = blockIdx.x * BN, m0 = blockIdx.y * BM;

    f32x4 acc[MT][NT] = {};

    const __bf16* Ab = A + (size_t)m0 * K;
    const __bf16* Bb = Bt + (size_t)n0 * K;
    int srow = lane >> 2;                                  // 0..15
    int scol = ((lane & 3) ^ ((lane >> 3) & 3)) * 8;       // pre-swizzled source slot
    int kx   = (q ^ ((ln >> 1) & 3)) * 8;                  // read-side swizzled slot

    const __bf16* Aga[ACH];
    const __bf16* Bga[BCH];
    #pragma unroll
    for (int i = 0; i < ACH; i++)
        Aga[i] = Ab + (size_t)(wave * (16 * ACH) + 16 * i + srow) * K + scol;
    #pragma unroll
    for (int i = 0; i < BCH; i++)
        Bga[i] = Bb + (size_t)(wave * (16 * BCH) + 16 * i + srow) * K + scol;

    auto STAGE = [&](int kp, int buf) {
        #pragma unroll
        for (int i = 0; i < ACH; i++)
            gl_lds16(Aga[i] + kp, As[buf] + (wave * (16 * ACH) + 16 * i) * 32);
        #pragma unroll
        for (int i = 0; i < BCH; i++)
            gl_lds16(Bga[i] + kp, Bs[buf] + (wave * (16 * BCH) + 16 * i) * 32);
    };
    auto COMPUTE = [&](int buf) {
        bf16x8 af[MT], bfr[NT];
        #pragma unroll
        for (int mt = 0; mt < MT; mt++)
            af[mt] = *(const bf16x8*)&As[buf][(wrow + mt * 16 + ln) * 32 + kx];
        #pragma unroll
        for (int nt = 0; nt < NT; nt++)
            bfr[nt] = *(const bf16x8*)&Bs[buf][(wcol + nt * 16 + ln) * 32 + kx];
        #pragma unroll
        for (int mt = 0; mt < MT; mt++)
            #pragma unroll
            for (int nt = 0; nt < NT; nt++)
                acc[mt][nt] = __builtin_amdgcn_mfma_f32_16x16x32_bf16(af[mt], bfr[nt], acc[mt][nt], 0, 0, 0);
    };

    STAGE(0, 0);
    __syncthreads();
    int kp = 0;
    for (; kp + 64 < K; kp += 64) {
        STAGE(kp + 32, 1);
        COMPUTE(0);
        __syncthreads();      // drain: panel kp+32 landed; buf0 readers done
        STAGE(kp + 64, 0);
        COMPUTE(1);
        __syncthreads();      // drain: panel kp+64 landed; buf1 readers done
    }
    STAGE(kp + 32, 1);
    COMPUTE(0);
    __syncthreads();
    COMPUTE(1);

    #pragma unroll
    for (int mt = 0; mt < MT; mt++) {
        int mbase = m0 + wrow + mt * 16 + q * 4;
        if constexpr (MODE == 0) {
            __bf16* Cb = (__bf16*)Cv;
            #pragma unroll
            for (int r = 0; r < 4; r++) {
                int m = mbase + r;
                #pragma unroll
                for (int nt = 0; nt < NT; nt++) {
                    int c = n0 + wcol + nt * 16 + ln;
                    Cb[(size_t)m * Nc + c] = (__bf16)(acc[mt][nt][r] + bias[c]);
                }
            }
        } else if constexpr (MODE == 1) {
            __bf16* Cb = (__bf16*)Cv;
            #pragma unroll
            for (int r = 0; r < 4; r++) {
                int m = mbase + r;
                #pragma unroll
                for (int nt = 0; nt < NT; nt++) {
                    int c = n0 + wcol + nt * 16 + ln;
                    float val = acc[mt][nt][r] + bias[c];
                    Cb[(size_t)m * Nc + c] = (__bf16)fmaxf(val, 0.f);
                }
            }
        } else {
            __bf16* Cb = (__bf16*)Cv;
            int n = mbase >> 10, t = mbase & (TT - 1);
            #pragma unroll
            for (int nt = 0; nt < NT; nt++) {
                int c = n0 + wcol + nt * 16 + ln;
                int buf = c >> 9;            // uniform within the 16-col group
                int hd = c & 511;
                int hh = hd >> 6, d = hd & 63;
                float bv = bias[c];
                if (buf == 2) {              // V^T [n,h,d,t]: 4 consecutive t -> one 8B store
                    size_t idx = 2 * (size_t)PERBUF + (((size_t)(n * NHD + hh) * 64 + d) << 10) + t;
                    bf16x4 v4;
                    #pragma unroll
                    for (int r = 0; r < 4; r++) v4[r] = (__bf16)(acc[mt][nt][r] + bv);
                    *(bf16x4*)&Cb[idx] = v4;
                } else {                     // Q,K [n,h,t,d]
                    size_t base = (size_t)buf * PERBUF + (((size_t)(n * NHD + hh) * TT + t) << 6) + d;
                    #pragma unroll
                    for (int r = 0; r < 4; r++)
                        Cb[base + (size_t)(r << 6)] = (__bf16)(acc[mt][nt][r] + bv);
                }
            }
        }
    }
}

// ---------------- split-KV MFMA flash attention (NCHUNK=24, table-driven) ----------------
// Q fragments in registers. K single-buffered + V double-buffered in LDS via
// async global_load_lds with XOR-swizzled source (linear dest, swizzled read).
// QK^T computed SWAPPED (S^T = K Q^T): lane holds 4 consecutive s per q-row ->
// P store is 4x bf16x4, den reduction 2 shuffles. 768 blocks (3/CU), chains <= 8.
// po partials stored BF16 (R8): MFMA accum stays f32; only the final per-chunk
// partial is quantized (~0.4% rel, ~2e-4 absolute after normalization).
#define PPAD 72
__global__ __launch_bounds__(256) void attn_partial_kernel(const __bf16* __restrict__ qb,
    const __bf16* __restrict__ kb, const __bf16* __restrict__ vtb,
    __bf16* __restrict__ po, float* __restrict__ pden)
{
    __shared__ __align__(16) __bf16 Ksh[64 * 64];      // K tile [s][d], swizzled
    __shared__ __align__(16) __bf16 Vsh[2][64 * 64];   // V^T tile [d][s], swizzled
    __shared__ __align__(16) __bf16 Ps[64 * PPAD];     // P tile [q][s], padded

    int u = blockIdx.x;                  // heavy chunks at low u (dispatch first)
    int nh = blockIdx.y;
    int qt  = C_QT[u];
    int st0 = C_ST0[u];
    int st1 = C_ST1[u];

    int tid = threadIdx.x;
    int lane = tid & 63, w = tid >> 6;
    int ln = lane & 15, q = lane >> 4;

    const __bf16* Kg = kb + (size_t)nh * TT * 64;
    const __bf16* Vg = vtb + (size_t)nh * 64 * TT;   // [d][t]

    // Q fragments in registers: wave w owns q-rows w*16..+16 of this q-tile
    const __bf16* Qrow = qb + ((size_t)nh * TT + (size_t)qt * 64 + w * 16 + ln) * 64;
    bf16x8 aq0 = *(const bf16x8*)(Qrow + q * 8);
    bf16x8 aq1 = *(const bf16x8*)(Qrow + 32 + q * 8);

    // staging geometry: wave w issue i covers LDS bytes [(w*2+i)*1024, +1024)
    // lane l -> row (w*2+i)*8 + (l>>3), col16 l&7; source col pre-swizzled.
    int srow = lane >> 3;                        // 0..7  == (row & 7)
    int swz  = ((lane & 7) ^ srow) << 3;         // swizzled source col (elems)
    int r0 = (w * 2 + 0) * 8 + srow;
    int r1 = (w * 2 + 1) * 8 + srow;
    const __bf16* Kg0 = Kg + (size_t)r0 * 64 + swz;
    const __bf16* Kg1 = Kg + (size_t)r1 * 64 + swz;
    const __bf16* Vg0 = Vg + (size_t)r0 * TT + swz;
    const __bf16* Vg1 = Vg + (size_t)r1 * TT + swz;
    __bf16* Kd0 = Ksh + (w * 2 + 0) * 512;
    __bf16* Kd1 = Ksh + (w * 2 + 1) * 512;

    f32x4 o_acc[4] = {};
    float den_lane = 0.f;          // partial softmax denom for q-row w*16+ln
    int qrow_l = w * 16 + ln;

    int cur = 0;
    gl_lds16(Kg0 + st0 * 4096, Kd0);
    gl_lds16(Kg1 + st0 * 4096, Kd1);
    gl_lds16(Vg0 + st0 * 64, Vsh[0] + (w * 2 + 0) * 512);
    gl_lds16(Vg1 + st0 * 64, Vsh[0] + (w * 2 + 1) * 512);

    int kswz = ln & 7;   // row&7 for all swizzled reads below (rows stride 16)
    for (int st = st0; st < st1; st++) {
        __syncthreads();   // staged K/V landed (vmcnt drain); prior P/V readers done

        // S^T = K Q^T: wave w computes S^T[all 64 s][its 16 q-cols]
        f32x4 st_acc[4] = {};
        #pragma unroll
        for (int mt = 0; mt < 4; mt++) {
            int r = mt * 16 + ln;
            bf16x8 k0v = *(const bf16x8*)&Ksh[r * 64 + ((q ^ kswz) << 3)];
            st_acc[mt] = __builtin_amdgcn_mfma_f32_16x16x32_bf16(k0v, aq0, st_acc[mt], 0, 0, 0);
            bf16x8 k1v = *(const bf16x8*)&Ksh[r * 64 + (((q + 4) ^ kswz) << 3)];
            st_acc[mt] = __builtin_amdgcn_mfma_f32_16x16x32_bf16(k1v, aq1, st_acc[mt], 0, 0, 0);
        }

        // P = exp(S/8), causal mask on diagonal tile. Lane holds 4 consecutive s
        // (mt*16 + q*4 + r) for its q-row -> one bf16x4 store per mt.
        bool diag = (st == qt);
        #pragma unroll
        for (int mt = 0; mt < 4; mt++) {
            int s0i = mt * 16 + q * 4;
            bf16x4 p4;
            #pragma unroll
            for (int r = 0; r < 4; r++) {
                float p;
                if (diag && (s0i + r) > qrow_l) p = 0.f;
                else p = exp2f(st_acc[mt][r] * 0.18033688011112042f);  // /8 * log2(e)
                den_lane += p;
                p4[r] = (__bf16)p;
            }
            *(bf16x4*)&Ps[qrow_l * PPAD + s0i] = p4;
        }
        __syncthreads();   // P visible; all waves done reading K

        if (st + 1 < st1) {   // prefetch next tile under PV (K dead, V alt buffer)
            gl_lds16(Kg0 + (st + 1) * 4096, Kd0);
            gl_lds16(Kg1 + (st + 1) * 4096, Kd1);
            gl_lds16(Vg0 + (st + 1) * 64, Vsh[cur ^ 1] + (w * 2 + 0) * 512);
            gl_lds16(Vg1 + (st + 1) * 64, Vsh[cur ^ 1] + (w * 2 + 1) * 512);
        }

        // O^T += V^T P^T : wave w owns d-rows w*16..+16, all 64 q-cols
        #pragma unroll
        for (int ks = 0; ks < 2; ks++) {
            bf16x8 af = *(const bf16x8*)&Vsh[cur][(w * 16 + ln) * 64 + (((ks * 4 + q) ^ kswz) << 3)];
            #pragma unroll
            for (int nt = 0; nt < 4; nt++) {
                bf16x8 bfr = *(const bf16x8*)&Ps[(nt * 16 + ln) * PPAD + ks * 32 + q * 8];
                o_acc[nt] = __builtin_amdgcn_mfma_f32_16x16x32_bf16(af, bfr, o_acc[nt], 0, 0, 0);
            }
        }
        cur ^= 1;
    }

    // den: lanes {ln, ln+16, ln+32, ln+48} hold s-partitions of q-row w*16+ln
    den_lane += __shfl_xor(den_lane, 16, 64);
    den_lane += __shfl_xor(den_lane, 32, 64);
    size_t slot = (size_t)nh * NCHUNK + u;
    if (lane < 16)
        pden[slot * 64 + qrow_l] = den_lane;

    #pragma unroll
    for (int nt = 0; nt < 4; nt++) {
        bf16x4 ov;
        #pragma unroll
        for (int r = 0; r < 4; r++) ov[r] = (__bf16)o_acc[nt][r];
        *(bf16x4*)&po[(slot << 12) + (size_t)(nt * 16 + ln) * 64 + w * 16 + q * 4] = ov;
    }
}

// ---------------- fused split-KV combine + residual + LayerNorm ----------------
__global__ __launch_bounds__(256) void add_ln_attn_kernel(float* __restrict__ h,
    __bf16* __restrict__ hb, const __bf16* __restrict__ po, const float* __restrict__ pden,
    const float* __restrict__ g, const float* __restrict__ b)
{
    int w = threadIdx.x >> 6, lane = threadIdx.x & 63;
    int row = (blockIdx.x << 2) + w;          // n*1024 + t
    int n = row >> 10, t = row & (TT - 1);
    int qt = t >> 6, qrow = t & 63;
    int hh = lane >> 3;
    int d0 = (lane & 7) * 8;
    size_t base_nh = (size_t)(n * NHD + hh) * NCHUNK;

    size_t sa = base_nh + C_UA[qt];
    bf16x8 va = *(const bf16x8*)(po + (sa << 12) + (size_t)qrow * 64 + d0);
    float den = pden[sa * 64 + qrow];
    f32x4 a0, a1;
    #pragma unroll
    for (int i = 0; i < 4; i++) { a0[i] = (float)va[i]; a1[i] = (float)va[4 + i]; }
    if (qt >= 8) {
        size_t sb = base_nh + C_UB[qt];
        bf16x8 vb = *(const bf16x8*)(po + (sb << 12) + (size_t)qrow * 64 + d0);
        #pragma unroll
        for (int i = 0; i < 4; i++) { a0[i] += (float)vb[i]; a1[i] += (float)vb[4 + i]; }
        den += pden[sb * 64 + qrow];
    }
    float inv = 1.0f / den;

    size_t base = (size_t)row * DM + lane * 8;
    f32x4 x0 = *(const f32x4*)&h[base];
    f32x4 x1 = *(const f32x4*)&h[base + 4];
    x0 += a0 * inv;
    x1 += a1 * inv;

    float s1 = x0[0]+x0[1]+x0[2]+x0[3] + x1[0]+x1[1]+x1[2]+x1[3];
    float s2 = x0[0]*x0[0]+x0[1]*x0[1]+x0[2]*x0[2]+x0[3]*x0[3]
             + x1[0]*x1[0]+x1[1]*x1[1]+x1[2]*x1[2]+x1[3]*x1[3];
    #pragma unroll
    for (int m = 1; m < 64; m <<= 1) {
        s1 += __shfl_xor(s1, m, 64);
        s2 += __shfl_xor(s2, m, 64);
    }
    float mean = s1 * (1.0f / 512.0f);
    float var = s2 * (1.0f / 512.0f) - mean * mean;
    float rstd = rsqrtf(var + 1e-3f);

    f32x4 gg0 = *(const f32x4*)&g[lane * 8];
    f32x4 gg1 = *(const f32x4*)&g[lane * 8 + 4];
    f32x4 bb0 = *(const f32x4*)&b[lane * 8];
    f32x4 bb1 = *(const f32x4*)&b[lane * 8 + 4];
    f32x4 o0, o1;
    bf16x8 pb;
    #pragma unroll
    for (int i = 0; i < 4; i++) {
        o0[i] = gg0[i] * ((x0[i] - mean) * rstd) + bb0[i];
        o1[i] = gg1[i] * ((x1[i] - mean) * rstd) + bb1[i];
        pb[i] = (__bf16)o0[i];
        pb[4 + i] = (__bf16)o1[i];
    }
    *(f32x4*)&h[base] = o0;
    *(f32x4*)&h[base + 4] = o1;
    *(bf16x8*)(hb + base) = pb;
}

// ---------------- residual add (bf16 ff out) + LayerNorm (one wave per row) ----------------
__global__ __launch_bounds__(256) void add_ln_kernel(float* __restrict__ h,
    __bf16* __restrict__ hb, const __bf16* __restrict__ a,
    const float* __restrict__ g, const float* __restrict__ b)
{
    int w = threadIdx.x >> 6, lane = threadIdx.x & 63;
    int row = (blockIdx.x << 2) + w;
    size_t base4 = (size_t)row * (DM / 4);
    const float4* h4 = (const float4*)h;
    float4 x0 = h4[base4 + lane];
    float4 x1 = h4[base4 + 64 + lane];
    const __bf16* arow = a + (size_t)row * DM;
    bf16x4 y0 = *(const bf16x4*)&arow[lane * 4];
    bf16x4 y1 = *(const bf16x4*)&arow[256 + lane * 4];
    x0.x += (float)y0[0]; x0.y += (float)y0[1]; x0.z += (float)y0[2]; x0.w += (float)y0[3];
    x1.x += (float)y1[0]; x1.y += (float)y1[1]; x1.z += (float)y1[2]; x1.w += (float)y1[3];
    float s1 = x0.x + x0.y + x0.z + x0.w + x1.x + x1.y + x1.z + x1.w;
    float s2 = x0.x*x0.x + x0.y*x0.y + x0.z*x0.z + x0.w*x0.w
             + x1.x*x1.x + x1.y*x1.y + x1.z*x1.z + x1.w*x1.w;
    #pragma unroll
    for (int m = 1; m < 64; m <<= 1) {
        s1 += __shfl_xor(s1, m, 64);
        s2 += __shfl_xor(s2, m, 64);
    }
    float mean = s1 * (1.0f / 512.0f);
    float var = s2 * (1.0f / 512.0f) - mean * mean;
    float rstd = rsqrtf(var + 1e-3f);
    const float4* g4 = (const float4*)g;
    const float4* b4 = (const float4*)b;
    float4 gg0 = g4[lane], gg1 = g4[64 + lane];
    float4 bb0 = b4[lane], bb1 = b4[64 + lane];
    float4 o0, o1;
    o0.x = gg0.x * ((x0.x - mean) * rstd) + bb0.x;
    o0.y = gg0.y * ((x0.y - mean) * rstd) + bb0.y;
    o0.z = gg0.z * ((x0.z - mean) * rstd) + bb0.z;
    o0.w = gg0.w * ((x0.w - mean) * rstd) + bb0.w;
    o1.x = gg1.x * ((x1.x - mean) * rstd) + bb1.x;
    o1.y = gg1.y * ((x1.y - mean) * rstd) + bb1.y;
    o1.z = gg1.z * ((x1.z - mean) * rstd) + bb1.z;
    o1.w = gg1.w * ((x1.w - mean) * rstd) + bb1.w;
    ((float4*)h)[base4 + lane] = o0;
    ((float4*)h)[base4 + 64 + lane] = o1;
    bf16x4 p0, p1;
    p0[0] = (__bf16)o0.x; p0[1] = (__bf16)o0.y; p0[2] = (__bf16)o0.z; p0[3] = (__bf16)o0.w;
    p1[0] = (__bf16)o1.x; p1[1] = (__bf16)o1.y; p1[2] = (__bf16)o1.z; p1[3] = (__bf16)o1.w;
    *(bf16x4*)(hb + (size_t)row * DM + lane * 4) = p0;
    *(bf16x4*)(hb + (size_t)row * DM + 256 + lane * 4) = p1;
}

extern "C" void kernel_launch(void* const* d_in, const int* in_sizes, int n_in,
                              void* d_out, int out_size, void* d_ws, size_t ws_size,
                              hipStream_t stream) {
    const int*   x     = (const int*)d_in[0];
    const float* emb   = (const float*)d_in[1];
    const float* Wqkv  = (const float*)d_in[2];
    const float* bqkv  = (const float*)d_in[3];
    const float* Wff   = (const float*)d_in[4];
    const float* bff   = (const float*)d_in[5];
    const float* Wo    = (const float*)d_in[6];
    const float* bo    = (const float*)d_in[7];
    const float* g1    = (const float*)d_in[8];
    const float* beta1 = (const float*)d_in[9];
    const float* g2    = (const float*)d_in[10];
    const float* beta2 = (const float*)d_in[11];

    float* h = (float*)d_out;               // [4096, 512] running hidden state
    char* w = (char*)d_ws;
    __bf16* qkvb = (__bf16*)w;                        // 12,582,912 B (Q|K|V^T bf16)
    __bf16* ffb  = (__bf16*)w;                        // aliases qkv (dead after attn)
    __bf16* abuf = (__bf16*)(w + 25165824);           //  4,194,304 B (FF2 out, bf16)
    __bf16* hb   = (__bf16*)(w + 33554432);           //  4,194,304 B
    __bf16* WtQ  = (__bf16*)(w + 37748736);           //  9,437,184 B  [L][1536][512] (perm'd rows)
    __bf16* WtF  = (__bf16*)(w + 47185920);           //  6,291,456 B  [L][1024][512]
    __bf16* WtO  = (__bf16*)(w + 53477376);           //  6,291,456 B  [L][512][1024]
    __bf16* po   = (__bf16*)(w + 59768832);           //  6,291,456 B  [32*24][64][64] bf16
    float*  pden = (float*)(w + 80740352);            //    196,608 B  [32*24][64]
    float*  bqkv_p = (float*)(w + 81068032);          //     36,864 B  [L][1536] perm'd bias

    convert_all_kernel<<<dim3(1792, 1, LAYERS), 256, 0, stream>>>(
        Wqkv, Wff, Wo, bqkv, WtQ, WtF, WtO, bqkv_p);

    embed_pos_kernel<<<MROWS, 256, 0, stream>>>(x, emb, h, hb);

    for (int l = 0; l < LAYERS; l++) {
        const float* bff_l  = bff  + (size_t)l * DFFD;
        const float* bo_l   = bo   + (size_t)l * DM;

        // QKV projection: 128x64 tiles -> 768 blocks (3/CU)
        gemm2p<128, 64, 2><<<dim3(24, 32), 256, 0, stream>>>(
            hb, WtQ + (size_t)l * 1536 * 512, bqkv_p + l * 1536, qkvb, MROWS, 3 * DM, 512);

        attn_partial_kernel<<<dim3(NCHUNK, NB * NHD), 256, 0, stream>>>(
            qkvb, qkvb + PERBUF, qkvb + 2 * (size_t)PERBUF, po, pden);

        // fused: combine split-KV partials + residual + LN1
        add_ln_attn_kernel<<<MROWS / 4, 256, 0, stream>>>(
            h, hb, po, pden, g1 + l * DM, beta1 + l * DM);

        // FF1: relu(h @ Wff + bff) -> bf16; 128x64 tiles -> 512 blocks (2/CU)
        gemm2p<128, 64, 1><<<dim3(16, 32), 256, 0, stream>>>(
            hb, WtF + (size_t)l * 1024 * 512, bff_l, ffb, MROWS, DFFD, 512);

        // FF2: ff @ Wo + bo -> bf16; 64x64 tiles -> 512 blocks (2/CU)
        gemm2p<64, 64, 0><<<dim3(8, 64), 256, 0, stream>>>(
            ffb, WtO + (size_t)l * 512 * 1024, bo_l, abuf, MROWS, DM, 1024);

        add_ln_kernel<<<MROWS / 4, 256, 0, stream>>>(h, hb, abuf, g2 + l * DM, beta2 + l * DM);
    }
}

// Round 10
// 593.001 us; speedup vs baseline: 1.3960x; 1.0366x over previous
//
#include <hip/hip_runtime.h>
#include <hip/hip_bf16.h>
#include <math.h>

#define DM   512
#define TT   1024
#define NB   4
#define NHD  8
#define LAYERS 6
#define DFFD 1024
#define MROWS (NB*TT)          // 4096
#define PERBUF (NB*NHD*TT*64)  // 2097152 elems per Q/K/V buffer

typedef __bf16 bf16x8 __attribute__((ext_vector_type(8)));
typedef __bf16 bf16x4 __attribute__((ext_vector_type(4)));
typedef float f32x4 __attribute__((ext_vector_type(4)));

// async global->LDS, 16B per lane; LDS base must be wave-uniform (m104/m108)
__device__ __forceinline__ void gl_lds16(const __bf16* g, __bf16* l) {
    __builtin_amdgcn_global_load_lds((const __attribute__((address_space(1))) void*)g,
                                     (__attribute__((address_space(3))) void*)l, 16, 0, 0);
}

// split-KV chunk tables (NCHUNK=24): qt 0-7 one chunk, qt 8-15 two chunks.
// Ordered heavy-first (u=0 dispatched first carries longest chains).
__constant__ signed char C_QT[24]  = {15,15,14, 7,14,13,13,12, 6,12,11,11,10, 5,10, 9, 9, 8, 4, 8, 3, 2, 1, 0};
__constant__ signed char C_ST0[24] = { 0, 8, 0, 0, 8, 0, 7, 0, 0, 7, 0, 6, 0, 0, 6, 0, 5, 0, 0, 5, 0, 0, 0, 0};
__constant__ signed char C_ST1[24] = { 8,16, 8, 8,15, 7,14, 7, 7,13, 6,12, 6, 6,11, 5,10, 5, 5, 9, 4, 3, 2, 1};
// combine: qt -> chunk ids (second valid only for qt>=8)
__constant__ unsigned char C_UA[16] = {23,22,21,20,18,13,8,3,17,15,12,10,7,5,2,0};
__constant__ unsigned char C_UB[16] = { 0, 0, 0, 0, 0, 0,0,0,19,16,14,11,9,6,4,1};
#define NCHUNK 24

// ---------------- embedding + positional encoding (bf16 residual stream) ----------------
// R9: residual carry is bf16-only (hb); no f32 h store. Fast trig (exp2f, __sincosf).
__global__ __launch_bounds__(256) void embed_pos_kernel(const int* __restrict__ x,
    const float* __restrict__ emb, __bf16* __restrict__ hb)
{
    int row = blockIdx.x;            // n*T + t
    int t = row & (TT - 1);
    int tok = x[row];
    const float* e = emb + (size_t)tok * DM;
    __bf16* outb = hb + (size_t)row * DM;
    for (int i = threadIdx.x; i < DM; i += 256) {
        float val = e[i] * 22.62741699796952f;   // sqrt(512)
        int pair = i >> 1;
        // 10000^(-pair/256) = exp2(-pair * log2(10000)/256)
        float rate = exp2f((float)pair * -0.051905126482615035f);
        float ang = (float)t * rate;
        float pe = (i & 1) ? __cosf(ang) : __sinf(ang);
        outb[i] = (__bf16)(val + pe);
    }
}

// ---------------- all-weight convert + transpose (one dispatch) ----------------
// W[K,N] fp32 -> Wt[N,K] bf16. For Wqkv, output columns are PERMUTED:
// original col c -> row (c%3)*512 + c/3, grouping Q|K|V with inner [h][d].
__global__ __launch_bounds__(256) void convert_all_kernel(
    const float* __restrict__ Wqkv, const float* __restrict__ Wff, const float* __restrict__ Wo,
    const float* __restrict__ bqkv,
    __bf16* __restrict__ WtQ, __bf16* __restrict__ WtF, __bf16* __restrict__ WtO,
    float* __restrict__ bqkv_p)
{
    __shared__ float tile[32][33];
    int l = blockIdx.z;
    int t = blockIdx.x;
    const float* W; __bf16* Wt; int K, N, bx, by; bool perm = false;
    if (t < 768)       { W = Wqkv; Wt = WtQ; K = 512;  N = 1536; bx = t & 15;  by = t >> 4; perm = true; }
    else if (t < 1280) { int u = t - 768;  W = Wff; Wt = WtF; K = 512;  N = 1024; bx = u & 15; by = u >> 4; }
    else               { int u = t - 1280; W = Wo;  Wt = WtO; K = 1024; N = 512;  bx = u & 31; by = u >> 5; }
    int k0 = bx * 32, n0 = by * 32;
    const float* Wl = W + (size_t)l * K * N;
    __bf16* Wtl = Wt + (size_t)l * K * N;
    int tx = threadIdx.x & 31, ty = threadIdx.x >> 5;   // ty 0..7
    #pragma unroll
    for (int i = ty; i < 32; i += 8)
        tile[i][tx] = Wl[(size_t)(k0 + i) * N + n0 + tx];
    if (perm && bx == 0 && ty == 0) {                   // permute bias once per col-chunk
        int c = n0 + tx;
        bqkv_p[l * 1536 + (c % 3) * 512 + c / 3] = bqkv[(size_t)l * 1536 + c];
    }
    __syncthreads();
    #pragma unroll
    for (int i = ty; i < 32; i += 8) {
        int c = n0 + i;
        int row = perm ? ((c % 3) * 512 + c / 3) : c;
        Wtl[(size_t)row * K + k0 + tx] = (__bf16)tile[tx][i];
    }
}

// ---------------- bf16 MFMA GEMM, templated tile, 2-phase pipelined 32-K panels ----------------
// LDS reads swizzled conflict-free (R7); 2-3 blocks/CU (R5). Fragment loads via LDS (R4 lesson).
// MODE 0: bf16 C out (+bias, no relu). MODE 1: relu -> bf16. MODE 2: QKV scatter, PERMUTED cols:
// c in [0,512)=Q, [512,1024)=K (both [n,h,t,d]), [1024,1536)=V^T [n,h,d,t].
template<int BM, int BN, int MODE>
__global__ __launch_bounds__(256) void gemm2p(const __bf16* __restrict__ A,
    const __bf16* __restrict__ Bt, const float* __restrict__ bias,
    void* __restrict__ Cv, int M, int Nc, int K)
{
    constexpr int WM = BM / 2, WN = BN / 2;
    constexpr int MT = WM / 16, NT = WN / 16;
    constexpr int ACH = BM / 64;   // 16-row A chunks staged per wave
    constexpr int BCH = BN / 64;   // 16-row B chunks staged per wave
    __shared__ __align__(16) __bf16 As[2][BM * 32];
    __shared__ __align__(16) __bf16 Bs[2][BN * 32];
    int tid = threadIdx.x;
    int lane = tid & 63;
    int wave = tid >> 6;
    int ln = lane & 15, q = lane >> 4;
    int wrow = (wave >> 1) * WM, wcol = (wave & 1) * WN;
    int n0 = blockIdx.x * BN, m0 = blockIdx.y * BM;

    f32x4 acc[MT][NT] = {};

    const __bf16* Ab = A + (size_t)m0 * K;
    const __bf16* Bb = Bt + (size_t)n0 * K;
    int srow = lane >> 2;                                  // 0..15
    int scol = ((lane & 3) ^ ((lane >> 3) & 3)) * 8;       // pre-swizzled source slot
    int kx   = (q ^ ((ln >> 1) & 3)) * 8;                  // read-side swizzled slot

    const __bf16* Aga[ACH];
    const __bf16* Bga[BCH];
    #pragma unroll
    for (int i = 0; i < ACH; i++)
        Aga[i] = Ab + (size_t)(wave * (16 * ACH) + 16 * i + srow) * K + scol;
    #pragma unroll
    for (int i = 0; i < BCH; i++)
        Bga[i] = Bb + (size_t)(wave * (16 * BCH) + 16 * i + srow) * K + scol;

    auto STAGE = [&](int kp, int buf) {
        #pragma unroll
        for (int i = 0; i < ACH; i++)
            gl_lds16(Aga[i] + kp, As[buf] + (wave * (16 * ACH) + 16 * i) * 32);
        #pragma unroll
        for (int i = 0; i < BCH; i++)
            gl_lds16(Bga[i] + kp, Bs[buf] + (wave * (16 * BCH) + 16 * i) * 32);
    };
    auto COMPUTE = [&](int buf) {
        bf16x8 af[MT], bfr[NT];
        #pragma unroll
        for (int mt = 0; mt < MT; mt++)
            af[mt] = *(const bf16x8*)&As[buf][(wrow + mt * 16 + ln) * 32 + kx];
        #pragma unroll
        for (int nt = 0; nt < NT; nt++)
            bfr[nt] = *(const bf16x8*)&Bs[buf][(wcol + nt * 16 + ln) * 32 + kx];
        #pragma unroll
        for (int mt = 0; mt < MT; mt++)
            #pragma unroll
            for (int nt = 0; nt < NT; nt++)
                acc[mt][nt] = __builtin_amdgcn_mfma_f32_16x16x32_bf16(af[mt], bfr[nt], acc[mt][nt], 0, 0, 0);
    };

    STAGE(0, 0);
    __syncthreads();
    int kp = 0;
    for (; kp + 64 < K; kp += 64) {
        STAGE(kp + 32, 1);
        COMPUTE(0);
        __syncthreads();      // drain: panel kp+32 landed; buf0 readers done
        STAGE(kp + 64, 0);
        COMPUTE(1);
        __syncthreads();      // drain: panel kp+64 landed; buf1 readers done
    }
    STAGE(kp + 32, 1);
    COMPUTE(0);
    __syncthreads();
    COMPUTE(1);

    #pragma unroll
    for (int mt = 0; mt < MT; mt++) {
        int mbase = m0 + wrow + mt * 16 + q * 4;
        if constexpr (MODE == 0) {
            __bf16* Cb = (__bf16*)Cv;
            #pragma unroll
            for (int r = 0; r < 4; r++) {
                int m = mbase + r;
                #pragma unroll
                for (int nt = 0; nt < NT; nt++) {
                    int c = n0 + wcol + nt * 16 + ln;
                    Cb[(size_t)m * Nc + c] = (__bf16)(acc[mt][nt][r] + bias[c]);
                }
            }
        } else if constexpr (MODE == 1) {
            __bf16* Cb = (__bf16*)Cv;
            #pragma unroll
            for (int r = 0; r < 4; r++) {
                int m = mbase + r;
                #pragma unroll
                for (int nt = 0; nt < NT; nt++) {
                    int c = n0 + wcol + nt * 16 + ln;
                    float val = acc[mt][nt][r] + bias[c];
                    Cb[(size_t)m * Nc + c] = (__bf16)fmaxf(val, 0.f);
                }
            }
        } else {
            __bf16* Cb = (__bf16*)Cv;
            int n = mbase >> 10, t = mbase & (TT - 1);
            #pragma unroll
            for (int nt = 0; nt < NT; nt++) {
                int c = n0 + wcol + nt * 16 + ln;
                int buf = c >> 9;            // uniform within the 16-col group
                int hd = c & 511;
                int hh = hd >> 6, d = hd & 63;
                float bv = bias[c];
                if (buf == 2) {              // V^T [n,h,d,t]: 4 consecutive t -> one 8B store
                    size_t idx = 2 * (size_t)PERBUF + (((size_t)(n * NHD + hh) * 64 + d) << 10) + t;
                    bf16x4 v4;
                    #pragma unroll
                    for (int r = 0; r < 4; r++) v4[r] = (__bf16)(acc[mt][nt][r] + bv);
                    *(bf16x4*)&Cb[idx] = v4;
                } else {                     // Q,K [n,h,t,d]
                    size_t base = (size_t)buf * PERBUF + (((size_t)(n * NHD + hh) * TT + t) << 6) + d;
                    #pragma unroll
                    for (int r = 0; r < 4; r++)
                        Cb[base + (size_t)(r << 6)] = (__bf16)(acc[mt][nt][r] + bv);
                }
            }
        }
    }
}

// ---------------- split-KV MFMA flash attention (NCHUNK=24, table-driven) ----------------
// Q fragments in registers. K single-buffered + V double-buffered in LDS via
// async global_load_lds with XOR-swizzled source (linear dest, swizzled read).
// QK^T computed SWAPPED (S^T = K Q^T): lane holds 4 consecutive s per q-row ->
// P store is 4x bf16x4, den reduction 2 shuffles. 768 blocks (3/CU), chains <= 8.
// po partials stored BF16 (R8): MFMA accum stays f32.
#define PPAD 72
__global__ __launch_bounds__(256) void attn_partial_kernel(const __bf16* __restrict__ qb,
    const __bf16* __restrict__ kb, const __bf16* __restrict__ vtb,
    __bf16* __restrict__ po, float* __restrict__ pden)
{
    __shared__ __align__(16) __bf16 Ksh[64 * 64];      // K tile [s][d], swizzled
    __shared__ __align__(16) __bf16 Vsh[2][64 * 64];   // V^T tile [d][s], swizzled
    __shared__ __align__(16) __bf16 Ps[64 * PPAD];     // P tile [q][s], padded

    int u = blockIdx.x;                  // heavy chunks at low u (dispatch first)
    int nh = blockIdx.y;
    int qt  = C_QT[u];
    int st0 = C_ST0[u];
    int st1 = C_ST1[u];

    int tid = threadIdx.x;
    int lane = tid & 63, w = tid >> 6;
    int ln = lane & 15, q = lane >> 4;

    const __bf16* Kg = kb + (size_t)nh * TT * 64;
    const __bf16* Vg = vtb + (size_t)nh * 64 * TT;   // [d][t]

    // Q fragments in registers: wave w owns q-rows w*16..+16 of this q-tile
    const __bf16* Qrow = qb + ((size_t)nh * TT + (size_t)qt * 64 + w * 16 + ln) * 64;
    bf16x8 aq0 = *(const bf16x8*)(Qrow + q * 8);
    bf16x8 aq1 = *(const bf16x8*)(Qrow + 32 + q * 8);

    // staging geometry: wave w issue i covers LDS bytes [(w*2+i)*1024, +1024)
    // lane l -> row (w*2+i)*8 + (l>>3), col16 l&7; source col pre-swizzled.
    int srow = lane >> 3;                        // 0..7  == (row & 7)
    int swz  = ((lane & 7) ^ srow) << 3;         // swizzled source col (elems)
    int r0 = (w * 2 + 0) * 8 + srow;
    int r1 = (w * 2 + 1) * 8 + srow;
    const __bf16* Kg0 = Kg + (size_t)r0 * 64 + swz;
    const __bf16* Kg1 = Kg + (size_t)r1 * 64 + swz;
    const __bf16* Vg0 = Vg + (size_t)r0 * TT + swz;
    const __bf16* Vg1 = Vg + (size_t)r1 * TT + swz;
    __bf16* Kd0 = Ksh + (w * 2 + 0) * 512;
    __bf16* Kd1 = Ksh + (w * 2 + 1) * 512;

    f32x4 o_acc[4] = {};
    float den_lane = 0.f;          // partial softmax denom for q-row w*16+ln
    int qrow_l = w * 16 + ln;

    int cur = 0;
    gl_lds16(Kg0 + st0 * 4096, Kd0);
    gl_lds16(Kg1 + st0 * 4096, Kd1);
    gl_lds16(Vg0 + st0 * 64, Vsh[0] + (w * 2 + 0) * 512);
    gl_lds16(Vg1 + st0 * 64, Vsh[0] + (w * 2 + 1) * 512);

    int kswz = ln & 7;   // row&7 for all swizzled reads below (rows stride 16)
    for (int st = st0; st < st1; st++) {
        __syncthreads();   // staged K/V landed (vmcnt drain); prior P/V readers done

        // S^T = K Q^T: wave w computes S^T[all 64 s][its 16 q-cols]
        f32x4 st_acc[4] = {};
        #pragma unroll
        for (int mt = 0; mt < 4; mt++) {
            int r = mt * 16 + ln;
            bf16x8 k0v = *(const bf16x8*)&Ksh[r * 64 + ((q ^ kswz) << 3)];
            st_acc[mt] = __builtin_amdgcn_mfma_f32_16x16x32_bf16(k0v, aq0, st_acc[mt], 0, 0, 0);
            bf16x8 k1v = *(const bf16x8*)&Ksh[r * 64 + (((q + 4) ^ kswz) << 3)];
            st_acc[mt] = __builtin_amdgcn_mfma_f32_16x16x32_bf16(k1v, aq1, st_acc[mt], 0, 0, 0);
        }

        // P = exp(S/8), causal mask on diagonal tile. Lane holds 4 consecutive s
        // (mt*16 + q*4 + r) for its q-row -> one bf16x4 store per mt.
        bool diag = (st == qt);
        #pragma unroll
        for (int mt = 0; mt < 4; mt++) {
            int s0i = mt * 16 + q * 4;
            bf16x4 p4;
            #pragma unroll
            for (int r = 0; r < 4; r++) {
                float p;
                if (diag && (s0i + r) > qrow_l) p = 0.f;
                else p = exp2f(st_acc[mt][r] * 0.18033688011112042f);  // /8 * log2(e)
                den_lane += p;
                p4[r] = (__bf16)p;
            }
            *(bf16x4*)&Ps[qrow_l * PPAD + s0i] = p4;
        }
        __syncthreads();   // P visible; all waves done reading K

        if (st + 1 < st1) {   // prefetch next tile under PV (K dead, V alt buffer)
            gl_lds16(Kg0 + (st + 1) * 4096, Kd0);
            gl_lds16(Kg1 + (st + 1) * 4096, Kd1);
            gl_lds16(Vg0 + (st + 1) * 64, Vsh[cur ^ 1] + (w * 2 + 0) * 512);
            gl_lds16(Vg1 + (st + 1) * 64, Vsh[cur ^ 1] + (w * 2 + 1) * 512);
        }

        // O^T += V^T P^T : wave w owns d-rows w*16..+16, all 64 q-cols
        #pragma unroll
        for (int ks = 0; ks < 2; ks++) {
            bf16x8 af = *(const bf16x8*)&Vsh[cur][(w * 16 + ln) * 64 + (((ks * 4 + q) ^ kswz) << 3)];
            #pragma unroll
            for (int nt = 0; nt < 4; nt++) {
                bf16x8 bfr = *(const bf16x8*)&Ps[(nt * 16 + ln) * PPAD + ks * 32 + q * 8];
                o_acc[nt] = __builtin_amdgcn_mfma_f32_16x16x32_bf16(af, bfr, o_acc[nt], 0, 0, 0);
            }
        }
        cur ^= 1;
    }

    // den: lanes {ln, ln+16, ln+32, ln+48} hold s-partitions of q-row w*16+ln
    den_lane += __shfl_xor(den_lane, 16, 64);
    den_lane += __shfl_xor(den_lane, 32, 64);
    size_t slot = (size_t)nh * NCHUNK + u;
    if (lane < 16)
        pden[slot * 64 + qrow_l] = den_lane;

    #pragma unroll
    for (int nt = 0; nt < 4; nt++) {
        bf16x4 ov;
        #pragma unroll
        for (int r = 0; r < 4; r++) ov[r] = (__bf16)o_acc[nt][r];
        *(bf16x4*)&po[(slot << 12) + (size_t)(nt * 16 + ln) * 64 + w * 16 + q * 4] = ov;
    }
}

// ---------------- fused split-KV combine + residual + LayerNorm (bf16 stream) ----------------
__global__ __launch_bounds__(256) void add_ln_attn_kernel(__bf16* __restrict__ hb,
    const __bf16* __restrict__ po, const float* __restrict__ pden,
    const float* __restrict__ g, const float* __restrict__ b)
{
    int w = threadIdx.x >> 6, lane = threadIdx.x & 63;
    int row = (blockIdx.x << 2) + w;          // n*1024 + t
    int n = row >> 10, t = row & (TT - 1);
    int qt = t >> 6, qrow = t & 63;
    int hh = lane >> 3;
    int d0 = (lane & 7) * 8;
    size_t base_nh = (size_t)(n * NHD + hh) * NCHUNK;

    size_t sa = base_nh + C_UA[qt];
    bf16x8 va = *(const bf16x8*)(po + (sa << 12) + (size_t)qrow * 64 + d0);
    float den = pden[sa * 64 + qrow];
    f32x4 a0, a1;
    #pragma unroll
    for (int i = 0; i < 4; i++) { a0[i] = (float)va[i]; a1[i] = (float)va[4 + i]; }
    if (qt >= 8) {
        size_t sb = base_nh + C_UB[qt];
        bf16x8 vb = *(const bf16x8*)(po + (sb << 12) + (size_t)qrow * 64 + d0);
        #pragma unroll
        for (int i = 0; i < 4; i++) { a0[i] += (float)vb[i]; a1[i] += (float)vb[4 + i]; }
        den += pden[sb * 64 + qrow];
    }
    float inv = 1.0f / den;

    size_t base = (size_t)row * DM + lane * 8;
    bf16x8 hv = *(const bf16x8*)(hb + base);
    f32x4 x0, x1;
    #pragma unroll
    for (int i = 0; i < 4; i++) {
        x0[i] = (float)hv[i]     + a0[i] * inv;
        x1[i] = (float)hv[4 + i] + a1[i] * inv;
    }

    float s1 = x0[0]+x0[1]+x0[2]+x0[3] + x1[0]+x1[1]+x1[2]+x1[3];
    float s2 = x0[0]*x0[0]+x0[1]*x0[1]+x0[2]*x0[2]+x0[3]*x0[3]
             + x1[0]*x1[0]+x1[1]*x1[1]+x1[2]*x1[2]+x1[3]*x1[3];
    #pragma unroll
    for (int m = 1; m < 64; m <<= 1) {
        s1 += __shfl_xor(s1, m, 64);
        s2 += __shfl_xor(s2, m, 64);
    }
    float mean = s1 * (1.0f / 512.0f);
    float var = s2 * (1.0f / 512.0f) - mean * mean;
    float rstd = rsqrtf(var + 1e-3f);

    f32x4 gg0 = *(const f32x4*)&g[lane * 8];
    f32x4 gg1 = *(const f32x4*)&g[lane * 8 + 4];
    f32x4 bb0 = *(const f32x4*)&b[lane * 8];
    f32x4 bb1 = *(const f32x4*)&b[lane * 8 + 4];
    bf16x8 pb;
    #pragma unroll
    for (int i = 0; i < 4; i++) {
        pb[i]     = (__bf16)(gg0[i] * ((x0[i] - mean) * rstd) + bb0[i]);
        pb[4 + i] = (__bf16)(gg1[i] * ((x1[i] - mean) * rstd) + bb1[i]);
    }
    *(bf16x8*)(hb + base) = pb;
}

// ---------------- residual add (bf16 ff out) + LayerNorm (bf16 stream) ----------------
// fout != nullptr on the final layer: also writes the f32 output tensor.
__global__ __launch_bounds__(256) void add_ln_kernel(__bf16* __restrict__ hb,
    const __bf16* __restrict__ a, const float* __restrict__ g, const float* __restrict__ b,
    float* __restrict__ fout)
{
    int w = threadIdx.x >> 6, lane = threadIdx.x & 63;
    int row = (blockIdx.x << 2) + w;
    size_t base = (size_t)row * DM + lane * 8;
    bf16x8 hv = *(const bf16x8*)(hb + base);
    bf16x8 av = *(const bf16x8*)(a + base);
    f32x4 x0, x1;
    #pragma unroll
    for (int i = 0; i < 4; i++) {
        x0[i] = (float)hv[i]     + (float)av[i];
        x1[i] = (float)hv[4 + i] + (float)av[4 + i];
    }
    float s1 = x0[0]+x0[1]+x0[2]+x0[3] + x1[0]+x1[1]+x1[2]+x1[3];
    float s2 = x0[0]*x0[0]+x0[1]*x0[1]+x0[2]*x0[2]+x0[3]*x0[3]
             + x1[0]*x1[0]+x1[1]*x1[1]+x1[2]*x1[2]+x1[3]*x1[3];
    #pragma unroll
    for (int m = 1; m < 64; m <<= 1) {
        s1 += __shfl_xor(s1, m, 64);
        s2 += __shfl_xor(s2, m, 64);
    }
    float mean = s1 * (1.0f / 512.0f);
    float var = s2 * (1.0f / 512.0f) - mean * mean;
    float rstd = rsqrtf(var + 1e-3f);
    f32x4 gg0 = *(const f32x4*)&g[lane * 8];
    f32x4 gg1 = *(const f32x4*)&g[lane * 8 + 4];
    f32x4 bb0 = *(const f32x4*)&b[lane * 8];
    f32x4 bb1 = *(const f32x4*)&b[lane * 8 + 4];
    f32x4 o0, o1;
    bf16x8 pb;
    #pragma unroll
    for (int i = 0; i < 4; i++) {
        o0[i] = gg0[i] * ((x0[i] - mean) * rstd) + bb0[i];
        o1[i] = gg1[i] * ((x1[i] - mean) * rstd) + bb1[i];
        pb[i] = (__bf16)o0[i];
        pb[4 + i] = (__bf16)o1[i];
    }
    *(bf16x8*)(hb + base) = pb;
    if (fout) {
        *(f32x4*)&fout[base] = o0;
        *(f32x4*)&fout[base + 4] = o1;
    }
}

extern "C" void kernel_launch(void* const* d_in, const int* in_sizes, int n_in,
                              void* d_out, int out_size, void* d_ws, size_t ws_size,
                              hipStream_t stream) {
    const int*   x     = (const int*)d_in[0];
    const float* emb   = (const float*)d_in[1];
    const float* Wqkv  = (const float*)d_in[2];
    const float* bqkv  = (const float*)d_in[3];
    const float* Wff   = (const float*)d_in[4];
    const float* bff   = (const float*)d_in[5];
    const float* Wo    = (const float*)d_in[6];
    const float* bo    = (const float*)d_in[7];
    const float* g1    = (const float*)d_in[8];
    const float* beta1 = (const float*)d_in[9];
    const float* g2    = (const float*)d_in[10];
    const float* beta2 = (const float*)d_in[11];

    char* w = (char*)d_ws;
    __bf16* qkvb = (__bf16*)w;                        // 12,582,912 B (Q|K|V^T bf16)
    __bf16* ffb  = (__bf16*)w;                        // aliases qkv (dead after attn)
    __bf16* abuf = (__bf16*)(w + 25165824);           //  4,194,304 B (FF2 out, bf16)
    __bf16* hb   = (__bf16*)(w + 33554432);           //  4,194,304 B (bf16 residual stream)
    __bf16* WtQ  = (__bf16*)(w + 37748736);           //  9,437,184 B  [L][1536][512] (perm'd rows)
    __bf16* WtF  = (__bf16*)(w + 47185920);           //  6,291,456 B  [L][1024][512]
    __bf16* WtO  = (__bf16*)(w + 53477376);           //  6,291,456 B  [L][512][1024]
    __bf16* po   = (__bf16*)(w + 59768832);           //  6,291,456 B  [32*24][64][64] bf16
    float*  pden = (float*)(w + 80740352);            //    196,608 B  [32*24][64]
    float*  bqkv_p = (float*)(w + 81068032);          //     36,864 B  [L][1536] perm'd bias

    convert_all_kernel<<<dim3(1792, 1, LAYERS), 256, 0, stream>>>(
        Wqkv, Wff, Wo, bqkv, WtQ, WtF, WtO, bqkv_p);

    embed_pos_kernel<<<MROWS, 256, 0, stream>>>(x, emb, hb);

    for (int l = 0; l < LAYERS; l++) {
        const float* bff_l  = bff  + (size_t)l * DFFD;
        const float* bo_l   = bo   + (size_t)l * DM;

        // QKV projection: 128x64 tiles -> 768 blocks (3/CU)
        gemm2p<128, 64, 2><<<dim3(24, 32), 256, 0, stream>>>(
            hb, WtQ + (size_t)l * 1536 * 512, bqkv_p + l * 1536, qkvb, MROWS, 3 * DM, 512);

        attn_partial_kernel<<<dim3(NCHUNK, NB * NHD), 256, 0, stream>>>(
            qkvb, qkvb + PERBUF, qkvb + 2 * (size_t)PERBUF, po, pden);

        // fused: combine split-KV partials + residual + LN1 (bf16 stream)
        add_ln_attn_kernel<<<MROWS / 4, 256, 0, stream>>>(
            hb, po, pden, g1 + l * DM, beta1 + l * DM);

        // FF1: relu(h @ Wff + bff) -> bf16; 128x64 tiles -> 512 blocks (2/CU)
        gemm2p<128, 64, 1><<<dim3(16, 32), 256, 0, stream>>>(
            hb, WtF + (size_t)l * 1024 * 512, bff_l, ffb, MROWS, DFFD, 512);

        // FF2: ff @ Wo + bo -> bf16; 64x64 tiles -> 512 blocks (2/CU)
        gemm2p<64, 64, 0><<<dim3(8, 64), 256, 0, stream>>>(
            ffb, WtO + (size_t)l * 512 * 1024, bo_l, abuf, MROWS, DM, 1024);

        // residual + LN2; final layer also writes the f32 output
        add_ln_kernel<<<MROWS / 4, 256, 0, stream>>>(
            hb, abuf, g2 + l * DM, beta2 + l * DM,
            (l == LAYERS - 1) ? (float*)d_out : nullptr);
    }
}